// Round 1
// baseline (1955.891 us; speedup 1.0000x reference)
//
#include <hip/hip_runtime.h>
#include <hip/hip_bf16.h>

#define NRB 39936   // B*T = 1024*39
#define TT 39
#define CC 123      // NUM_C == H
#define EMBD 256

__device__ __forceinline__ float sigmoidf_(float x){ return 1.f/(1.f+__expf(-x)); }

// ---------------------------------------------------------------------------
// K0: rcontrib[which][j][h] = sum_i W[h][123+i] * answer_W[j][i]
//     which: 0=W_ih(stride 379), 1=W_z(stride 502), 2=W_h(stride 502)
__global__ void k_rcontrib(const float* __restrict__ W_ih, const float* __restrict__ W_z,
                           const float* __restrict__ W_h, const float* __restrict__ answer_W,
                           float* __restrict__ rtab)
{
  int which = blockIdx.x >> 1, j = blockIdx.x & 1;
  int h = threadIdx.x;
  if (h >= CC) return;
  const float* W; int stride;
  if (which==0){ W=W_ih; stride=379; } else if (which==1){ W=W_z; stride=502; } else { W=W_h; stride=502; }
  const float* a = answer_W + j*EMBD;
  const float* w = W + (size_t)h*stride + CC;
  float acc = 0.f;
  #pragma unroll 8
  for (int i=0;i<EMBD;i++) acc += w[i]*a[i];
  rtab[(which*2+j)*128 + h] = acc;
}

// ---------------------------------------------------------------------------
// K1a: per row: concept_ab = zz_W@q + zz_b; x1a = concept_ab * s_prof;
//      pre2 = e_disc*(d_t*s_prof - k_diff)*q;  cq = e_disc*(1-d_t)*q
__global__ __launch_bounds__(256) void k_prep(
    const float* __restrict__ q_m, const int* __restrict__ s_id, const int* __restrict__ e_id,
    const float* __restrict__ student_W, const float* __restrict__ k_diff_W,
    const float* __restrict__ e_disc_W, const float* __restrict__ zz_W,
    const float* __restrict__ zz_b, const float* __restrict__ d_t_p, const float* __restrict__ d_e_p,
    float* __restrict__ x1a, float* __restrict__ pre2, float* __restrict__ cq)
{
  __shared__ float WT[CC][128];   // transposed zz_W: WT[k][h]
  __shared__ float xs[2][128];
  const int tid = threadIdx.x;
  for (int i = tid; i < CC*CC; i += 256){ int h = i/CC, k = i - h*CC; WT[k][h] = zz_W[i]; }
  __syncthreads();
  const int group = tid >> 7, lane = tid & 127;
  const float dt = d_t_p[0], de = d_e_p[0];
  for (int rp = blockIdx.x; rp < NRB/2; rp += gridDim.x){
    int rrow = rp*2 + group;
    float qv = 0.f;
    if (lane < CC){ qv = q_m[(size_t)rrow*CC + lane]; xs[group][lane] = qv; }
    __syncthreads();
    if (lane < CC){
      float acc = zz_b[lane];
      #pragma unroll 4
      for (int k=0;k<CC;k++) acc += WT[k][lane]*xs[group][k];
      int b = rrow / TT;
      float sp = sigmoidf_(student_W[(size_t)s_id[b]*CC + lane]);
      x1a[(size_t)rrow*CC+lane] = acc*sp;
      int e = e_id[rrow];
      float kd = sigmoidf_(k_diff_W[(size_t)e*CC + lane]);
      float ed = sigmoidf_(e_disc_W[e]) * de;
      pre2[(size_t)rrow*CC+lane] = ed*(dt*sp - kd)*qv;
      cq[(size_t)rrow*CC+lane]   = ed*(1.f-dt)*qv;
    }
    __syncthreads();
  }
}

// ---------------------------------------------------------------------------
// Shared matvec: Y[r][h] = sum_{k<123} W[h][k]*X[r][k] + bias[h] + rtab[r_idx[r]][h]
__global__ __launch_bounds__(256) void k_mv123(
    const float* __restrict__ X, const float* __restrict__ W, int wstride,
    const float* __restrict__ bias, const float* __restrict__ rtab,
    const int* __restrict__ r_idx, float* __restrict__ Y)
{
  __shared__ float WT[CC][128];
  __shared__ float xs[2][128];
  const int tid = threadIdx.x;
  for (int i = tid; i < CC*CC; i += 256){ int h=i/CC, k=i-h*CC; WT[k][h] = W[(size_t)h*wstride + k]; }
  __syncthreads();
  const int group = tid>>7, lane = tid&127;
  for (int rp = blockIdx.x; rp < NRB/2; rp += gridDim.x){
    int rrow = rp*2+group;
    if (lane < CC) xs[group][lane] = X[(size_t)rrow*CC+lane];
    __syncthreads();
    if (lane < CC){
      float acc = bias[lane] + rtab[r_idx[rrow]*128 + lane];
      #pragma unroll 4
      for (int k=0;k<CC;k++) acc += WT[k][lane]*xs[group][k];
      Y[(size_t)rrow*CC+lane] = acc;
    }
    __syncthreads();
  }
}

// ---------------------------------------------------------------------------
// RNN1: h = tanh(Xp + W_hh@h + b_hh) * sigmoid(t*W_tg + b_tg)
__global__ __launch_bounds__(256) void k_rnn1(
    const float* __restrict__ Xp, const float* __restrict__ W_hh, const float* __restrict__ b_hh,
    const float* __restrict__ W_tg, const float* __restrict__ b_tg, float* __restrict__ outzz)
{
  __shared__ float WT[CC][128];
  __shared__ float hs[2][128];
  const int tid = threadIdx.x;
  for (int i=tid;i<CC*CC;i+=256){ int h=i/CC,k=i-h*CC; WT[k][h]=W_hh[i]; }
  const int group=tid>>7, lane=tid&127;
  hs[group][lane]=0.f;
  __syncthreads();
  const int b = blockIdx.x*2 + group;   // grid 512 -> b < 1024
  float bh=0.f, wg=0.f, bg=0.f;
  if (lane<CC){ bh=b_hh[lane]; wg=W_tg[lane]; bg=b_tg[lane]; }
  for (int t=0;t<TT;t++){
    float hnew=0.f;
    if (lane<CC){
      float acc = bh + Xp[((size_t)b*TT+t)*CC+lane];
      #pragma unroll 4
      for (int k=0;k<CC;k++) acc += WT[k][lane]*hs[group][k];
      hnew = tanhf(acc) * sigmoidf_((float)t*wg + bg);
    }
    __syncthreads();
    hs[group][lane]=hnew;
    __syncthreads();
    if (lane<CC) outzz[((size_t)b*TT+t)*CC+lane]=hnew;
  }
}

// ---------------------------------------------------------------------------
// x2a = pre2 + cq * outzz  (in place into pre2)
__global__ void k_x2a(float* __restrict__ pre2, const float* __restrict__ cq,
                      const float* __restrict__ outzz)
{
  size_t n = (size_t)NRB*CC;
  for (size_t i = (size_t)blockIdx.x*256 + threadIdx.x; i < n; i += (size_t)gridDim.x*256)
    pre2[i] += cq[i]*outzz[i];
}

// ---------------------------------------------------------------------------
// RNN2 (GRU-ish): z = sig(Zx + Wz_h@h); ht = tanh(Hx + Wh_h@h); h = (1-z)h + z*ht
// Wz_h = W_z[:,379:502], Wh_h = W_h[:,379:502]; staged bf16 (f32 pair won't fit 64KB)
__global__ __launch_bounds__(256) void k_rnn2(
    const float* __restrict__ Zx, const float* __restrict__ Hx,
    const float* __restrict__ W_z, const float* __restrict__ W_h, float* __restrict__ out2)
{
  __shared__ __hip_bfloat16 WzT[CC][128];
  __shared__ __hip_bfloat16 WhT[CC][128];
  __shared__ float hs[2][128];
  const int tid=threadIdx.x;
  for (int i=tid;i<CC*CC;i+=256){ int h=i/CC,k=i-h*CC;
    WzT[k][h]=__float2bfloat16(W_z[(size_t)h*502 + 379 + k]);
    WhT[k][h]=__float2bfloat16(W_h[(size_t)h*502 + 379 + k]); }
  const int group=tid>>7, lane=tid&127;
  hs[group][lane]=0.f;
  __syncthreads();
  const int b=blockIdx.x*2+group;
  for (int t=0;t<TT;t++){
    float hnew=0.f;
    if (lane<CC){
      size_t off=((size_t)b*TT+t)*CC+lane;
      float za=Zx[off], ha=Hx[off];
      #pragma unroll 2
      for (int k=0;k<CC;k++){ float hv=hs[group][k];
        za += __bfloat162float(WzT[k][lane])*hv;
        ha += __bfloat162float(WhT[k][lane])*hv; }
      float z=sigmoidf_(za);
      float th=tanhf(ha);
      hnew = (1.f-z)*hs[group][lane] + z*th;
    }
    __syncthreads();
    hs[group][lane]=hnew;
    __syncthreads();
    if (lane<CC) out2[((size_t)b*TT+t)*CC+lane]=hnew;
  }
}

// ---------------------------------------------------------------------------
// K5a: o1 = sigmoid(hcat @ p1_W.T + p1_b), hcat = [out2 | emb_problem[q_next] | q_m_next]
// 64-row x 256-col tile per block, 8x8 acc/thread, K chunks of 32.
__global__ __launch_bounds__(256) void k_o1(
    const float* __restrict__ out2, const float* __restrict__ emb_problem,
    const int* __restrict__ q_next, const float* __restrict__ q_m_next,
    const float* __restrict__ p1_W, const float* __restrict__ p1_b, float* __restrict__ o1)
{
  __shared__ float As[64][32];
  __shared__ float Bs[32][257];   // pad 257: staging (lane-varying kk) and reads stay conflict-free
  const int tid=threadIdx.x;
  const int colg = tid & 31;      // cols c = colg + 32*j
  const int m0 = (tid >> 5)*8;    // rows m0..m0+7
  const int rTile = blockIdx.x*64;
  float acc[8][8];
  #pragma unroll
  for (int i=0;i<8;i++){
    #pragma unroll
    for (int j=0;j<8;j++) acc[i][j]=0.f;
  }
  for (int k0=0;k0<502;k0+=32){
    #pragma unroll
    for (int i=0;i<8;i++){            // A: 64x32
      int id = tid + i*256;
      int rl = id >> 5, kk = id & 31;
      int k = k0 + kk;
      int rrow = rTile + rl;
      float v = 0.f;
      if (k < CC) v = out2[(size_t)rrow*CC + k];
      else if (k < CC+EMBD) v = emb_problem[(size_t)q_next[rrow]*EMBD + (k-CC)];
      else if (k < 502) v = q_m_next[(size_t)rrow*CC + (k-CC-EMBD)];
      As[rl][kk] = v;
    }
    #pragma unroll
    for (int i=0;i<32;i++){           // B: 32(k) x 256(out)
      int id = tid + i*256;
      int o = id >> 5, kk = id & 31;
      int k = k0 + kk;
      Bs[kk][o] = (k<502) ? p1_W[(size_t)o*502 + k] : 0.f;
    }
    __syncthreads();
    #pragma unroll 4
    for (int kk=0;kk<32;kk++){
      float a[8], bv[8];
      #pragma unroll
      for (int i=0;i<8;i++) a[i]=As[m0+i][kk];
      #pragma unroll
      for (int j=0;j<8;j++) bv[j]=Bs[kk][colg+32*j];
      #pragma unroll
      for (int i=0;i<8;i++){
        #pragma unroll
        for (int j=0;j<8;j++) acc[i][j] += a[i]*bv[j];
      }
    }
    __syncthreads();
  }
  #pragma unroll
  for (int j=0;j<8;j++){
    int c = colg + 32*j;
    float bb = p1_b[c];
    #pragma unroll
    for (int i=0;i<8;i++){
      int rrow = rTile + m0 + i;
      o1[(size_t)rrow*256 + c] = sigmoidf_(acc[i][j] + bb);
    }
  }
}

// ---------------------------------------------------------------------------
// K5b: o2 = sigmoid(o1 @ p2_W.T + p2_b) (123 cols), then out = sigmoid(p3.o2 + p3_b)
__global__ __launch_bounds__(256) void k_o2(
    const float* __restrict__ o1, const float* __restrict__ p2_W, const float* __restrict__ p2_b,
    const float* __restrict__ p3_W, const float* __restrict__ p3_b, float* __restrict__ out)
{
  __shared__ float As[64][32];
  __shared__ float Bs[32][129];
  __shared__ float os[64][129];
  const int tid=threadIdx.x;
  const int colg = tid & 31;      // cols c = colg + 32*j, j<4
  const int m0 = (tid>>5)*8;
  const int rTile = blockIdx.x*64;
  float acc[8][4];
  #pragma unroll
  for (int i=0;i<8;i++){
    #pragma unroll
    for (int j=0;j<4;j++) acc[i][j]=0.f;
  }
  for (int k0=0;k0<256;k0+=32){
    #pragma unroll
    for (int i=0;i<8;i++){
      int id = tid + i*256;
      int rl=id>>5, kk=id&31;
      As[rl][kk] = o1[(size_t)(rTile+rl)*256 + k0+kk];
    }
    #pragma unroll
    for (int i=0;i<16;i++){           // 32(k) x 128(out, 123 used)
      int id = tid + i*256;
      int c = id>>5, kk = id&31;
      Bs[kk][c] = (c<CC)? p2_W[(size_t)c*256 + k0+kk] : 0.f;
    }
    __syncthreads();
    #pragma unroll 4
    for (int kk=0;kk<32;kk++){
      float a[8], bv[4];
      #pragma unroll
      for (int i=0;i<8;i++) a[i]=As[m0+i][kk];
      #pragma unroll
      for (int j=0;j<4;j++) bv[j]=Bs[kk][colg+32*j];
      #pragma unroll
      for (int i=0;i<8;i++){
        #pragma unroll
        for (int j=0;j<4;j++) acc[i][j] += a[i]*bv[j];
      }
    }
    __syncthreads();
  }
  #pragma unroll
  for (int j=0;j<4;j++){
    int c = colg+32*j;
    float bb = (c<CC)? p2_b[c] : 0.f;
    #pragma unroll
    for (int i=0;i<8;i++)
      os[m0+i][c] = (c<CC)? sigmoidf_(acc[i][j]+bb) : 0.f;
  }
  __syncthreads();
  if (tid < 64){
    float acc3 = p3_b[0];
    #pragma unroll 4
    for (int c=0;c<CC;c++) acc3 += p3_W[c]*os[tid][c];
    out[rTile + tid] = sigmoidf_(acc3);
  }
}

// ---------------------------------------------------------------------------
extern "C" void kernel_launch(void* const* d_in, const int* in_sizes, int n_in,
                              void* d_out, int out_size, void* d_ws, size_t ws_size,
                              hipStream_t stream) {
  const float* q_m       = (const float*)d_in[0];
  const float* q_m_next  = (const float*)d_in[1];
  // d_in[2] concept: unused
  const int*   s_id      = (const int*)d_in[3];
  const int*   e_id      = (const int*)d_in[4];
  const int*   r_idx     = (const int*)d_in[5];
  const int*   q_next    = (const int*)d_in[6];
  // d_in[7] concept_next: unused
  const float* emb_problem = (const float*)d_in[8];
  const float* student_W = (const float*)d_in[9];
  const float* k_diff_W  = (const float*)d_in[10];
  const float* e_disc_W  = (const float*)d_in[11];
  const float* answer_W  = (const float*)d_in[12];
  const float* zz_W      = (const float*)d_in[13];
  const float* zz_b      = (const float*)d_in[14];
  const float* d_t       = (const float*)d_in[15];
  const float* d_e       = (const float*)d_in[16];
  const float* W_ih      = (const float*)d_in[17];
  const float* b_ih      = (const float*)d_in[18];
  const float* W_hh      = (const float*)d_in[19];
  const float* b_hh      = (const float*)d_in[20];
  const float* W_tg      = (const float*)d_in[21];
  const float* b_tg      = (const float*)d_in[22];
  const float* W_z       = (const float*)d_in[23];
  const float* b_z       = (const float*)d_in[24];
  const float* W_h       = (const float*)d_in[25];
  const float* b_h       = (const float*)d_in[26];
  const float* p1_W      = (const float*)d_in[27];
  const float* p1_b      = (const float*)d_in[28];
  const float* p2_W      = (const float*)d_in[29];
  const float* p2_b      = (const float*)d_in[30];
  const float* p3_W      = (const float*)d_in[31];
  const float* p3_b      = (const float*)d_in[32];

  const size_t NRC = (size_t)NRB*CC;
  float* ws   = (float*)d_ws;
  float* rtab = ws;            // 1024
  float* R1   = ws + 1024;     // x1a, later Zx
  float* R2   = R1 + NRC;      // Xp, later Hx
  float* R3   = R2 + NRC;      // pre2 -> x2a
  float* R4   = R3 + NRC;      // cq
  float* R5   = R4 + NRC;      // outzz, later out2
  float* R6   = R5 + NRC;      // o1 (NRB*256)

  hipLaunchKernelGGL(k_rcontrib, dim3(6), dim3(128), 0, stream,
                     W_ih, W_z, W_h, answer_W, rtab);
  hipLaunchKernelGGL(k_prep, dim3(512), dim3(256), 0, stream,
                     q_m, s_id, e_id, student_W, k_diff_W, e_disc_W, zz_W, zz_b,
                     d_t, d_e, R1, R3, R4);
  hipLaunchKernelGGL(k_mv123, dim3(512), dim3(256), 0, stream,
                     R1, W_ih, 379, b_ih, rtab + 0, r_idx, R2);          // Xp
  hipLaunchKernelGGL(k_rnn1, dim3(512), dim3(256), 0, stream,
                     R2, W_hh, b_hh, W_tg, b_tg, R5);                    // outzz
  hipLaunchKernelGGL(k_x2a, dim3(2048), dim3(256), 0, stream, R3, R4, R5); // x2a in R3
  hipLaunchKernelGGL(k_mv123, dim3(512), dim3(256), 0, stream,
                     R3, W_z, 502, b_z, rtab + 256, r_idx, R1);          // Zx
  hipLaunchKernelGGL(k_mv123, dim3(512), dim3(256), 0, stream,
                     R3, W_h, 502, b_h, rtab + 512, r_idx, R2);          // Hx
  hipLaunchKernelGGL(k_rnn2, dim3(512), dim3(256), 0, stream,
                     R1, R2, W_z, W_h, R5);                              // out2
  hipLaunchKernelGGL(k_o1, dim3(NRB/64), dim3(256), 0, stream,
                     R5, emb_problem, q_next, q_m_next, p1_W, p1_b, R6);
  hipLaunchKernelGGL(k_o2, dim3(NRB/64), dim3(256), 0, stream,
                     R6, p2_W, p2_b, p3_W, p3_b, (float*)d_out);
}

// Round 2
// 1408.147 us; speedup vs baseline: 1.3890x; 1.3890x over previous
//
#include <hip/hip_runtime.h>
#include <hip/hip_bf16.h>

#define NRB 39936   // B*T = 1024*39
#define TT 39
#define CC 123      // NUM_C == H
#define EMBD 256

typedef __attribute__((ext_vector_type(8))) short short8;
typedef __attribute__((ext_vector_type(4))) float floatx4;

__device__ __forceinline__ float sigmoidf_(float x){ return 1.f/(1.f+__expf(-x)); }

__device__ __forceinline__ unsigned short f2bf(float x){
  union { float f; unsigned u; } v; v.f = x;
  unsigned r = v.u + 0x7FFFu + ((v.u >> 16) & 1u);
  return (unsigned short)(r >> 16);
}

// async global->LDS, 16B per lane; LDS dest = wave-uniform base + lane*16
__device__ __forceinline__ void gl_lds16(void* lds, const void* g){
  __builtin_amdgcn_global_load_lds(
      (const __attribute__((address_space(1))) unsigned int*)g,
      (__attribute__((address_space(3))) unsigned int*)lds, 16, 0, 0);
}

// ---------------------------------------------------------------------------
// K0: rcontrib[which][j][h] = sum_i W[h][123+i] * answer_W[j][i]
__global__ void k_rcontrib(const float* __restrict__ W_ih, const float* __restrict__ W_z,
                           const float* __restrict__ W_h, const float* __restrict__ answer_W,
                           float* __restrict__ rtab)
{
  int which = blockIdx.x >> 1, j = blockIdx.x & 1;
  int h = threadIdx.x;
  if (h >= CC) return;
  const float* W; int stride;
  if (which==0){ W=W_ih; stride=379; } else if (which==1){ W=W_z; stride=502; } else { W=W_h; stride=502; }
  const float* a = answer_W + j*EMBD;
  const float* w = W + (size_t)h*stride + CC;
  float acc = 0.f;
  #pragma unroll 8
  for (int i=0;i<EMBD;i++) acc += w[i]*a[i];
  rtab[(which*2+j)*128 + h] = acc;
}

// ---------------------------------------------------------------------------
// k_convB: p1_W (256x502) -> p1bf[256][512] zero-padded bf16;
//          p2_W (123x256) -> p2bf[128][256] zero-padded bf16
__global__ __launch_bounds__(256) void k_convB(
    const float* __restrict__ p1_W, const float* __restrict__ p2_W,
    unsigned short* __restrict__ p1bf, unsigned short* __restrict__ p2bf)
{
  int i = blockIdx.x*256 + threadIdx.x;
  if (i < 256*512){
    int n = i >> 9, k = i & 511;
    p1bf[i] = f2bf(k < 502 ? p1_W[n*502 + k] : 0.f);
  }
  int j = i - 256*512;
  if (j >= 0 && j < 128*256){
    int n = j >> 8, k = j & 255;
    p2bf[j] = f2bf(n < 123 ? p2_W[n*256 + k] : 0.f);
  }
}

// ---------------------------------------------------------------------------
// k_hcat: fill Abf[NRB][512] cols [123,512): emb_problem[q_next] | q_m_next | 0
// (cols [0,123) are written later by k_rnn2)
__global__ __launch_bounds__(256) void k_hcat(
    const float* __restrict__ emb, const int* __restrict__ q_next,
    const float* __restrict__ qmn, unsigned short* __restrict__ Abf)
{
  const size_t total = (size_t)NRB*512;
  for (size_t i = (size_t)blockIdx.x*256 + threadIdx.x; i < total; i += (size_t)gridDim.x*256){
    int k = (int)(i & 511); size_t row = i >> 9;
    if (k < CC) continue;
    float v;
    if (k < CC+EMBD)      v = emb[(size_t)q_next[row]*EMBD + (k-CC)];
    else if (k < 502)     v = qmn[row*CC + (k-CC-EMBD)];
    else                  v = 0.f;
    Abf[i] = f2bf(v);
  }
}

// ---------------------------------------------------------------------------
// k_prep: concept_ab = zz_W@q + zz_b; x1a = concept_ab*s_prof;
//         pre2 = e_disc*(d_t*s_prof - k_diff)*q;  cq = e_disc*(1-d_t)*q
__global__ __launch_bounds__(256) void k_prep(
    const float* __restrict__ q_m, const int* __restrict__ s_id, const int* __restrict__ e_id,
    const float* __restrict__ student_W, const float* __restrict__ k_diff_W,
    const float* __restrict__ e_disc_W, const float* __restrict__ zz_W,
    const float* __restrict__ zz_b, const float* __restrict__ d_t_p, const float* __restrict__ d_e_p,
    float* __restrict__ x1a, float* __restrict__ pre2, float* __restrict__ cq)
{
  __shared__ float WT[CC][128];
  __shared__ float xs[2][128];
  const int tid = threadIdx.x;
  for (int i = tid; i < CC*CC; i += 256){ int h = i/CC, k = i - h*CC; WT[k][h] = zz_W[i]; }
  __syncthreads();
  const int group = tid >> 7, lane = tid & 127;
  const float dt = d_t_p[0], de = d_e_p[0];
  for (int rp = blockIdx.x; rp < NRB/2; rp += gridDim.x){
    int rrow = rp*2 + group;
    float qv = 0.f;
    if (lane < CC){ qv = q_m[(size_t)rrow*CC + lane]; xs[group][lane] = qv; }
    __syncthreads();
    if (lane < CC){
      float acc = zz_b[lane];
      #pragma unroll 4
      for (int k=0;k<CC;k++) acc += WT[k][lane]*xs[group][k];
      int b = rrow / TT;
      float sp = sigmoidf_(student_W[(size_t)s_id[b]*CC + lane]);
      x1a[(size_t)rrow*CC+lane] = acc*sp;
      int e = e_id[rrow];
      float kd = sigmoidf_(k_diff_W[(size_t)e*CC + lane]);
      float ed = sigmoidf_(e_disc_W[e]) * de;
      pre2[(size_t)rrow*CC+lane] = ed*(dt*sp - kd)*qv;
      cq[(size_t)rrow*CC+lane]   = ed*(1.f-dt)*qv;
    }
    __syncthreads();
  }
}

// ---------------------------------------------------------------------------
__global__ __launch_bounds__(256) void k_mv123(
    const float* __restrict__ X, const float* __restrict__ W, int wstride,
    const float* __restrict__ bias, const float* __restrict__ rtab,
    const int* __restrict__ r_idx, float* __restrict__ Y)
{
  __shared__ float WT[CC][128];
  __shared__ float xs[2][128];
  const int tid = threadIdx.x;
  for (int i = tid; i < CC*CC; i += 256){ int h=i/CC, k=i-h*CC; WT[k][h] = W[(size_t)h*wstride + k]; }
  __syncthreads();
  const int group = tid>>7, lane = tid&127;
  for (int rp = blockIdx.x; rp < NRB/2; rp += gridDim.x){
    int rrow = rp*2+group;
    if (lane < CC) xs[group][lane] = X[(size_t)rrow*CC+lane];
    __syncthreads();
    if (lane < CC){
      float acc = bias[lane] + rtab[r_idx[rrow]*128 + lane];
      #pragma unroll 4
      for (int k=0;k<CC;k++) acc += WT[k][lane]*xs[group][k];
      Y[(size_t)rrow*CC+lane] = acc;
    }
    __syncthreads();
  }
}

// ---------------------------------------------------------------------------
__global__ __launch_bounds__(256) void k_rnn1(
    const float* __restrict__ Xp, const float* __restrict__ W_hh, const float* __restrict__ b_hh,
    const float* __restrict__ W_tg, const float* __restrict__ b_tg, float* __restrict__ outzz)
{
  __shared__ float WT[CC][128];
  __shared__ float hs[2][128];
  const int tid = threadIdx.x;
  for (int i=tid;i<CC*CC;i+=256){ int h=i/CC,k=i-h*CC; WT[k][h]=W_hh[i]; }
  const int group=tid>>7, lane=tid&127;
  hs[group][lane]=0.f;
  __syncthreads();
  const int b = blockIdx.x*2 + group;
  float bh=0.f, wg=0.f, bg=0.f;
  if (lane<CC){ bh=b_hh[lane]; wg=W_tg[lane]; bg=b_tg[lane]; }
  for (int t=0;t<TT;t++){
    float hnew=0.f;
    if (lane<CC){
      float acc = bh + Xp[((size_t)b*TT+t)*CC+lane];
      #pragma unroll 4
      for (int k=0;k<CC;k++) acc += WT[k][lane]*hs[group][k];
      hnew = tanhf(acc) * sigmoidf_((float)t*wg + bg);
    }
    __syncthreads();
    hs[group][lane]=hnew;
    __syncthreads();
    if (lane<CC) outzz[((size_t)b*TT+t)*CC+lane]=hnew;
  }
}

// ---------------------------------------------------------------------------
__global__ void k_x2a(float* __restrict__ pre2, const float* __restrict__ cq,
                      const float* __restrict__ outzz)
{
  size_t n = (size_t)NRB*CC;
  for (size_t i = (size_t)blockIdx.x*256 + threadIdx.x; i < n; i += (size_t)gridDim.x*256)
    pre2[i] += cq[i]*outzz[i];
}

// ---------------------------------------------------------------------------
// RNN2: writes out2 as bf16 directly into hcat buffer Abf (cols 0..123)
__global__ __launch_bounds__(256) void k_rnn2(
    const float* __restrict__ Zx, const float* __restrict__ Hx,
    const float* __restrict__ W_z, const float* __restrict__ W_h,
    unsigned short* __restrict__ Abf)
{
  __shared__ __hip_bfloat16 WzT[CC][128];
  __shared__ __hip_bfloat16 WhT[CC][128];
  __shared__ float hs[2][128];
  const int tid=threadIdx.x;
  for (int i=tid;i<CC*CC;i+=256){ int h=i/CC,k=i-h*CC;
    WzT[k][h]=__float2bfloat16(W_z[(size_t)h*502 + 379 + k]);
    WhT[k][h]=__float2bfloat16(W_h[(size_t)h*502 + 379 + k]); }
  const int group=tid>>7, lane=tid&127;
  hs[group][lane]=0.f;
  __syncthreads();
  const int b=blockIdx.x*2+group;
  for (int t=0;t<TT;t++){
    float hnew=0.f;
    if (lane<CC){
      size_t off=((size_t)b*TT+t)*CC+lane;
      float za=Zx[off], ha=Hx[off];
      #pragma unroll 2
      for (int k=0;k<CC;k++){ float hv=hs[group][k];
        za += __bfloat162float(WzT[k][lane])*hv;
        ha += __bfloat162float(WhT[k][lane])*hv; }
      float z=sigmoidf_(za);
      float th=tanhf(ha);
      hnew = (1.f-z)*hs[group][lane] + z*th;
    }
    __syncthreads();
    hs[group][lane]=hnew;
    __syncthreads();
    if (lane<CC) Abf[((size_t)b*TT+t)*512 + lane] = f2bf(hnew);
  }
}

// ---------------------------------------------------------------------------
// k_o1_mfma: o1bf[NRB][256] = bf16(sigmoid(Abf @ p1bf^T + p1_b))
// Block: 64 rows x 256 cols, 4 waves (each wave: full 64 rows x 64-col strip).
// LDS seg-major layout [kseg][row][8 bf16]: fragment reads are lane-consecutive
// 16B (conflict-free) and global_load_lds dest is base + lane*16.
__global__ __launch_bounds__(256) void k_o1_mfma(
    const unsigned short* __restrict__ Abf, const unsigned short* __restrict__ p1bf,
    const float* __restrict__ p1_b, unsigned short* __restrict__ o1bf)
{
  __shared__ __align__(16) unsigned short Asl[8][64][8];   // 8 KB
  __shared__ __align__(16) unsigned short Bsl[8][256][8];  // 32 KB
  const int tid = threadIdx.x;
  const int w = tid >> 6, l = tid & 63;
  const int q = l >> 4, r16 = l & 15;
  const int rTile = blockIdx.x * 64;
  floatx4 acc[4][4];
  #pragma unroll
  for (int a=0;a<4;a++){
    #pragma unroll
    for (int b=0;b<4;b++){ acc[a][b][0]=0.f; acc[a][b][1]=0.f; acc[a][b][2]=0.f; acc[a][b][3]=0.f; }
  }
  for (int c = 0; c < 8; c++){
    const int k0 = c*64;
    #pragma unroll
    for (int i=0;i<2;i++){
      int u = i*256 + tid; int seg = u>>6, m = u&63;
      gl_lds16(&Asl[seg][m][0], Abf + (size_t)(rTile+m)*512 + k0 + seg*8);
    }
    #pragma unroll
    for (int i=0;i<8;i++){
      int u = i*256 + tid; int seg = u>>8, n = u&255;
      gl_lds16(&Bsl[seg][n][0], p1bf + (size_t)n*512 + k0 + seg*8);
    }
    __syncthreads();
    #pragma unroll
    for (int ks=0; ks<2; ks++){
      int seg = ks*4 + q;
      short8 af[4], bfr[4];
      #pragma unroll
      for (int mt=0;mt<4;mt++) af[mt] = *(const short8*)&Asl[seg][mt*16 + r16][0];
      #pragma unroll
      for (int nt=0;nt<4;nt++) bfr[nt] = *(const short8*)&Bsl[seg][w*64 + nt*16 + r16][0];
      #pragma unroll
      for (int mt=0;mt<4;mt++){
        #pragma unroll
        for (int nt=0;nt<4;nt++)
          acc[mt][nt] = __builtin_amdgcn_mfma_f32_16x16x32_bf16(af[mt], bfr[nt], acc[mt][nt], 0,0,0);
      }
    }
    __syncthreads();
  }
  #pragma unroll
  for (int nt=0;nt<4;nt++){
    int col = w*64 + nt*16 + r16;
    float bb = p1_b[col];
    #pragma unroll
    for (int mt=0;mt<4;mt++){
      #pragma unroll
      for (int i=0;i<4;i++){
        int row = rTile + mt*16 + q*4 + i;
        o1bf[(size_t)row*256 + col] = f2bf(sigmoidf_(acc[mt][nt][i] + bb));
      }
    }
  }
}

// ---------------------------------------------------------------------------
// k_o2_mfma: o2 = sigmoid(o1bf @ p2bf^T + p2_b) (123 cols, padded 128),
//            out = sigmoid(o2 @ p3_W + p3_b)  — fused in-block reduction.
__global__ __launch_bounds__(256) void k_o2_mfma(
    const unsigned short* __restrict__ o1bf, const unsigned short* __restrict__ p2bf,
    const float* __restrict__ p2_b, const float* __restrict__ p3_W,
    const float* __restrict__ p3_b, float* __restrict__ out)
{
  __shared__ __align__(16) unsigned short Asl[8][64][8];   // 8 KB
  __shared__ __align__(16) unsigned short Bsl[8][128][8];  // 16 KB
  __shared__ float red[64][4];
  const int tid = threadIdx.x;
  const int w = tid >> 6, l = tid & 63;
  const int q = l >> 4, r16 = l & 15;
  const int rTile = blockIdx.x * 64;
  floatx4 acc[4][2];
  #pragma unroll
  for (int a=0;a<4;a++){
    #pragma unroll
    for (int b=0;b<2;b++){ acc[a][b][0]=0.f; acc[a][b][1]=0.f; acc[a][b][2]=0.f; acc[a][b][3]=0.f; }
  }
  for (int c = 0; c < 4; c++){
    const int k0 = c*64;
    #pragma unroll
    for (int i=0;i<2;i++){
      int u = i*256 + tid; int seg = u>>6, m = u&63;
      gl_lds16(&Asl[seg][m][0], o1bf + (size_t)(rTile+m)*256 + k0 + seg*8);
    }
    #pragma unroll
    for (int i=0;i<4;i++){
      int u = i*256 + tid; int seg = u>>7, n = u&127;
      gl_lds16(&Bsl[seg][n][0], p2bf + (size_t)n*256 + k0 + seg*8);
    }
    __syncthreads();
    #pragma unroll
    for (int ks=0; ks<2; ks++){
      int seg = ks*4 + q;
      short8 af[4], bfr[2];
      #pragma unroll
      for (int mt=0;mt<4;mt++) af[mt] = *(const short8*)&Asl[seg][mt*16 + r16][0];
      #pragma unroll
      for (int nt=0;nt<2;nt++) bfr[nt] = *(const short8*)&Bsl[seg][w*32 + nt*16 + r16][0];
      #pragma unroll
      for (int mt=0;mt<4;mt++){
        #pragma unroll
        for (int nt=0;nt<2;nt++)
          acc[mt][nt] = __builtin_amdgcn_mfma_f32_16x16x32_bf16(af[mt], bfr[nt], acc[mt][nt], 0,0,0);
      }
    }
    __syncthreads();
  }
  const int n0 = w*32 + r16, n1 = n0 + 16;
  const float pb0 = (n0<CC)? p2_b[n0]:0.f, pb1 = (n1<CC)? p2_b[n1]:0.f;
  const float p30 = (n0<CC)? p3_W[n0]:0.f, p31 = (n1<CC)? p3_W[n1]:0.f;
  #pragma unroll
  for (int mt=0;mt<4;mt++){
    #pragma unroll
    for (int i=0;i<4;i++){
      float s = sigmoidf_(acc[mt][0][i]+pb0)*p30 + sigmoidf_(acc[mt][1][i]+pb1)*p31;
      s += __shfl_xor(s,1,16); s += __shfl_xor(s,2,16);
      s += __shfl_xor(s,4,16); s += __shfl_xor(s,8,16);
      if (r16==0) red[mt*16 + q*4 + i][w] = s;
    }
  }
  __syncthreads();
  if (tid < 64){
    float o = red[tid][0]+red[tid][1]+red[tid][2]+red[tid][3] + p3_b[0];
    out[rTile + tid] = sigmoidf_(o);
  }
}

// ---------------------------------------------------------------------------
extern "C" void kernel_launch(void* const* d_in, const int* in_sizes, int n_in,
                              void* d_out, int out_size, void* d_ws, size_t ws_size,
                              hipStream_t stream) {
  const float* q_m       = (const float*)d_in[0];
  const float* q_m_next  = (const float*)d_in[1];
  const int*   s_id      = (const int*)d_in[3];
  const int*   e_id      = (const int*)d_in[4];
  const int*   r_idx     = (const int*)d_in[5];
  const int*   q_next    = (const int*)d_in[6];
  const float* emb_problem = (const float*)d_in[8];
  const float* student_W = (const float*)d_in[9];
  const float* k_diff_W  = (const float*)d_in[10];
  const float* e_disc_W  = (const float*)d_in[11];
  const float* answer_W  = (const float*)d_in[12];
  const float* zz_W      = (const float*)d_in[13];
  const float* zz_b      = (const float*)d_in[14];
  const float* d_t       = (const float*)d_in[15];
  const float* d_e       = (const float*)d_in[16];
  const float* W_ih      = (const float*)d_in[17];
  const float* b_ih      = (const float*)d_in[18];
  const float* W_hh      = (const float*)d_in[19];
  const float* b_hh      = (const float*)d_in[20];
  const float* W_tg      = (const float*)d_in[21];
  const float* b_tg      = (const float*)d_in[22];
  const float* W_z       = (const float*)d_in[23];
  const float* b_z       = (const float*)d_in[24];
  const float* W_h       = (const float*)d_in[25];
  const float* b_h       = (const float*)d_in[26];
  const float* p1_W      = (const float*)d_in[27];
  const float* p1_b      = (const float*)d_in[28];
  const float* p2_W      = (const float*)d_in[29];
  const float* p2_b      = (const float*)d_in[30];
  const float* p3_W      = (const float*)d_in[31];
  const float* p3_b      = (const float*)d_in[32];

  const size_t NRC = (size_t)NRB*CC;
  float* ws   = (float*)d_ws;
  float* rtab = ws;            // 1024 f
  float* R1   = ws + 1024;     // x1a -> Zx
  float* R2   = R1 + NRC;      // Xp  -> Hx
  float* R3   = R2 + NRC;      // pre2 -> x2a
  float* R4   = R3 + NRC;      // cq   (dead after x2a)
  float* R5   = R4 + NRC;      // outzz (dead after x2a)
  unsigned short* Abf  = (unsigned short*)(R5 + NRC);   // [NRB][512] bf16
  unsigned short* p1bf = Abf + (size_t)NRB*512;         // [256][512]
  unsigned short* p2bf = p1bf + 256*512;                // [128][256]
  unsigned short* o1bf = (unsigned short*)R4;           // reuse R4+R5: [NRB][256]

  hipLaunchKernelGGL(k_rcontrib, dim3(6), dim3(128), 0, stream,
                     W_ih, W_z, W_h, answer_W, rtab);
  hipLaunchKernelGGL(k_convB, dim3(640), dim3(256), 0, stream,
                     p1_W, p2_W, p1bf, p2bf);
  hipLaunchKernelGGL(k_hcat, dim3(2048), dim3(256), 0, stream,
                     emb_problem, q_next, q_m_next, Abf);
  hipLaunchKernelGGL(k_prep, dim3(512), dim3(256), 0, stream,
                     q_m, s_id, e_id, student_W, k_diff_W, e_disc_W, zz_W, zz_b,
                     d_t, d_e, R1, R3, R4);
  hipLaunchKernelGGL(k_mv123, dim3(512), dim3(256), 0, stream,
                     R1, W_ih, 379, b_ih, rtab + 0, r_idx, R2);          // Xp
  hipLaunchKernelGGL(k_rnn1, dim3(512), dim3(256), 0, stream,
                     R2, W_hh, b_hh, W_tg, b_tg, R5);                    // outzz
  hipLaunchKernelGGL(k_x2a, dim3(2048), dim3(256), 0, stream, R3, R4, R5);
  hipLaunchKernelGGL(k_mv123, dim3(512), dim3(256), 0, stream,
                     R3, W_z, 502, b_z, rtab + 256, r_idx, R1);          // Zx
  hipLaunchKernelGGL(k_mv123, dim3(512), dim3(256), 0, stream,
                     R3, W_h, 502, b_h, rtab + 512, r_idx, R2);          // Hx
  hipLaunchKernelGGL(k_rnn2, dim3(512), dim3(256), 0, stream,
                     R1, R2, W_z, W_h, Abf);                             // out2 -> Abf[:, :123]
  hipLaunchKernelGGL(k_o1_mfma, dim3(NRB/64), dim3(256), 0, stream,
                     Abf, p1bf, p1_b, o1bf);
  hipLaunchKernelGGL(k_o2_mfma, dim3(NRB/64), dim3(256), 0, stream,
                     o1bf, p2bf, p2_b, p3_W, p3_b, (float*)d_out);
}

// Round 3
// 523.942 us; speedup vs baseline: 3.7330x; 2.6876x over previous
//
#include <hip/hip_runtime.h>
#include <hip/hip_bf16.h>

#define NRB 39936   // B*T = 1024*39
#define BB 1024
#define TT 39
#define CC 123      // NUM_C == H
#define EMBD 256

typedef __attribute__((ext_vector_type(8))) short short8;
typedef __attribute__((ext_vector_type(4))) float floatx4;

__device__ __forceinline__ float sigmoidf_(float x){ return 1.f/(1.f+__expf(-x)); }

__device__ __forceinline__ unsigned short f2bf(float x){
  union { float f; unsigned u; } v; v.f = x;
  unsigned r = v.u + 0x7FFFu + ((v.u >> 16) & 1u);
  return (unsigned short)(r >> 16);
}

// async global->LDS, 16B per lane; LDS dest = wave-uniform base + lane*16
__device__ __forceinline__ void gl_lds16(void* lds, const void* g){
  __builtin_amdgcn_global_load_lds(
      (const __attribute__((address_space(1))) unsigned int*)g,
      (__attribute__((address_space(3))) unsigned int*)lds, 16, 0, 0);
}

// ---------------------------------------------------------------------------
// K0: rtab[(which*2+r)*128+h] = sum_i W[h][123+i] * answer_W[r][i]
__global__ void k_rcontrib(const float* __restrict__ W_ih, const float* __restrict__ W_z,
                           const float* __restrict__ W_h, const float* __restrict__ answer_W,
                           float* __restrict__ rtab)
{
  int which = blockIdx.x >> 1, j = blockIdx.x & 1;
  int h = threadIdx.x;
  if (h >= CC) return;
  const float* W; int stride;
  if (which==0){ W=W_ih; stride=379; } else if (which==1){ W=W_z; stride=502; } else { W=W_h; stride=502; }
  const float* a = answer_W + j*EMBD;
  const float* w = W + (size_t)h*stride + CC;
  float acc = 0.f;
  #pragma unroll 8
  for (int i=0;i<EMBD;i++) acc += w[i]*a[i];
  rtab[(which*2+j)*128 + h] = acc;
}

// ---------------------------------------------------------------------------
// k_convW: 7x [128][128] bf16 weight matrices + p1bf[256][512] + p2bf[128][256]
// order: 0=zzW 1=Wih123 2=Wz123 3=Wh123 4=Whh 5=Wzh 6=Whh2
__global__ __launch_bounds__(256) void k_convW(
    const float* __restrict__ zz_W, const float* __restrict__ W_ih,
    const float* __restrict__ W_z, const float* __restrict__ W_h,
    const float* __restrict__ W_hh, const float* __restrict__ p1_W,
    const float* __restrict__ p2_W,
    unsigned short* __restrict__ wts, unsigned short* __restrict__ p1bf,
    unsigned short* __restrict__ p2bf)
{
  int i = blockIdx.x*256 + threadIdx.x;
  if (i < 7*16384){
    int w = i >> 14, idx = i & 16383, n = idx >> 7, k = idx & 127;
    float v = 0.f;
    if (n < CC && k < CC){
      if      (w==0) v = zz_W[n*CC + k];
      else if (w==1) v = W_ih[n*379 + k];
      else if (w==2) v = W_z [n*502 + k];
      else if (w==3) v = W_h [n*502 + k];
      else if (w==4) v = W_hh[n*CC + k];
      else if (w==5) v = W_z [n*502 + 379 + k];
      else           v = W_h [n*502 + 379 + k];
    }
    wts[i] = f2bf(v);
    return;
  }
  int j = i - 7*16384;
  if (j < 256*512){
    int n = j >> 9, k = j & 511;
    p1bf[j] = f2bf(k < 502 ? p1_W[n*502 + k] : 0.f);
    return;
  }
  j -= 256*512;
  if (j < 128*256){
    int n = j >> 8, k = j & 255;
    p2bf[j] = f2bf(n < CC ? p2_W[n*256 + k] : 0.f);
  }
}

// ---------------------------------------------------------------------------
// k_hcat: fill Abf[NRB][512] cols [123,512): emb_problem[q_next] | q_m_next | 0
__global__ __launch_bounds__(256) void k_hcat(
    const float* __restrict__ emb, const int* __restrict__ q_next,
    const float* __restrict__ qmn, unsigned short* __restrict__ Abf)
{
  const size_t total = (size_t)NRB*512;
  for (size_t i = (size_t)blockIdx.x*256 + threadIdx.x; i < total; i += (size_t)gridDim.x*256){
    int k = (int)(i & 511); size_t row = i >> 9;
    if (k < CC) continue;
    float v;
    if (k < CC+EMBD)      v = emb[(size_t)q_next[row]*EMBD + (k-CC)];
    else if (k < 502)     v = qmn[row*CC + (k-CC-EMBD)];
    else                  v = 0.f;
    Abf[i] = f2bf(v);
  }
}

// ---------------------------------------------------------------------------
// k_cast: qbf[t][b][128] bf16 from q_m[b][t][123]  (t-major)
__global__ __launch_bounds__(256) void k_cast(
    const float* __restrict__ q_m, unsigned short* __restrict__ qbf)
{
  const size_t total = (size_t)NRB*128;
  for (size_t i = (size_t)blockIdx.x*256 + threadIdx.x; i < total; i += (size_t)gridDim.x*256){
    int col = (int)(i & 127); size_t rp = i >> 7;
    int t = (int)(rp >> 10), b = (int)(rp & 1023);
    float v = (col < CC) ? q_m[((size_t)b*TT + t)*CC + col] : 0.f;
    qbf[i] = f2bf(v);
  }
}

// ---------------------------------------------------------------------------
// k_elem1 (t-major): x1abf = bf16(AB*sp); pre2 = ed*(dt*sp-kd)*q; cq = ed*(1-dt)*q
__global__ __launch_bounds__(256) void k_elem1(
    const float* __restrict__ AB, const float* __restrict__ q_m,
    const int* __restrict__ s_id, const int* __restrict__ e_id,
    const float* __restrict__ student_W, const float* __restrict__ k_diff_W,
    const float* __restrict__ e_disc_W, const float* __restrict__ d_t_p,
    const float* __restrict__ d_e_p,
    unsigned short* __restrict__ x1abf, float* __restrict__ pre2, float* __restrict__ cq)
{
  const float dt = d_t_p[0], de = d_e_p[0];
  const size_t total = (size_t)NRB*128;
  for (size_t i = (size_t)blockIdx.x*256 + threadIdx.x; i < total; i += (size_t)gridDim.x*256){
    int col = (int)(i & 127); size_t rp = i >> 7;
    int t = (int)(rp >> 10), b = (int)(rp & 1023);
    size_t g = (size_t)b*TT + t;
    if (col < CC){
      float ab = AB[i];
      float qv = q_m[g*CC + col];
      float sp = sigmoidf_(student_W[(size_t)s_id[b]*CC + col]);
      int e = e_id[g];
      float kd = sigmoidf_(k_diff_W[(size_t)e*CC + col]);
      float ed = sigmoidf_(e_disc_W[e]) * de;
      x1abf[i] = f2bf(ab*sp);
      pre2[i]  = ed*(dt*sp - kd)*qv;
      cq[i]    = ed*(1.f-dt)*qv;
    } else {
      x1abf[i] = 0; pre2[i] = 0.f; cq[i] = 0.f;
    }
  }
}

// ---------------------------------------------------------------------------
// k_bgemm: Y[M][128] = X[M][128]bf16 @ W[128][128]bf16^T + bias (+ rtab[r])
// 64 rows/block, 4 waves x 2 n-tiles, B-frags in registers, A via global_load_lds.
__global__ __launch_bounds__(256) void k_bgemm(
    const unsigned short* __restrict__ X, const unsigned short* __restrict__ W,
    const float* __restrict__ bias, const float* __restrict__ rtp, int rtmode,
    const int* __restrict__ r_idx, float* __restrict__ Y)
{
  __shared__ __align__(16) unsigned short Asl[16][64][8];   // 16 KB
  const int tid = threadIdx.x, w = tid >> 6, l = tid & 63, q = l >> 4, r16 = l & 15;
  const int rTile = blockIdx.x*64;
  short8 bfr[2][4];
  #pragma unroll
  for (int nt=0;nt<2;nt++){
    int n = w*32 + nt*16 + r16;
    #pragma unroll
    for (int kt=0;kt<4;kt++)
      bfr[nt][kt] = *(const short8*)(W + (size_t)n*128 + kt*32 + q*8);
  }
  #pragma unroll
  for (int i=0;i<4;i++){
    int seg = i*4 + w;
    gl_lds16(&Asl[seg][l][0], X + (size_t)(rTile+l)*128 + seg*8);
  }
  floatx4 acc[4][2];
  #pragma unroll
  for (int mt=0;mt<4;mt++){
    #pragma unroll
    for (int nt=0;nt<2;nt++){ acc[mt][nt][0]=0.f; acc[mt][nt][1]=0.f; acc[mt][nt][2]=0.f; acc[mt][nt][3]=0.f; }
  }
  __syncthreads();
  #pragma unroll
  for (int kt=0;kt<4;kt++){
    short8 af[4];
    #pragma unroll
    for (int mt=0;mt<4;mt++) af[mt] = *(const short8*)&Asl[kt*4+q][mt*16+r16][0];
    #pragma unroll
    for (int mt=0;mt<4;mt++){
      #pragma unroll
      for (int nt=0;nt<2;nt++)
        acc[mt][nt] = __builtin_amdgcn_mfma_f32_16x16x32_bf16(af[mt], bfr[nt][kt], acc[mt][nt], 0,0,0);
    }
  }
  float bb[2], rv0[2], rv1[2];
  #pragma unroll
  for (int nt=0;nt<2;nt++){
    int col = w*32 + nt*16 + r16;
    bb[nt] = (col < CC) ? bias[col] : 0.f;
    rv0[nt] = rtmode ? rtp[col]       : 0.f;
    rv1[nt] = rtmode ? rtp[128 + col] : 0.f;
  }
  #pragma unroll
  for (int mt=0;mt<4;mt++){
    #pragma unroll
    for (int i=0;i<4;i++){
      int row = rTile + mt*16 + q*4 + i;
      int rsel = 0;
      if (rtmode){ int orig = (row & 1023)*TT + (row >> 10); rsel = r_idx[orig]; }
      #pragma unroll
      for (int nt=0;nt<2;nt++){
        int col = w*32 + nt*16 + r16;
        float rv = rtmode ? (rsel ? rv1[nt] : rv0[nt]) : 0.f;
        Y[(size_t)row*128 + col] = acc[mt][nt][i] + bb[nt] + rv;
      }
    }
  }
}

// ---------------------------------------------------------------------------
// k_rnn1_mfma: h_t = tanh(Xp_t + h@Whh^T)*g(t);  x2abf = bf16(pre2 + cq*h)
// 64 blocks x 16 batch rows; Xp/pre2/cq/x2abf t-major [t][b][128].
__global__ __launch_bounds__(256) void k_rnn1_mfma(
    const float* __restrict__ Xp, const float* __restrict__ pre2, const float* __restrict__ cq,
    const unsigned short* __restrict__ Whh, const float* __restrict__ W_tg,
    const float* __restrict__ b_tg, unsigned short* __restrict__ x2abf)
{
  __shared__ __align__(16) unsigned short hls[2][16][144];  // 9216 B
  const int tid = threadIdx.x, w = tid >> 6, l = tid & 63, q = l >> 4, r16 = l & 15;
  const int bbase = blockIdx.x*16;
  short8 bfr[2][4];
  float wgv[2], bgv[2];
  int col_[2];
  #pragma unroll
  for (int nt=0;nt<2;nt++){
    int n = w*32 + nt*16 + r16; col_[nt] = n;
    #pragma unroll
    for (int kt=0;kt<4;kt++)
      bfr[nt][kt] = *(const short8*)(Whh + (size_t)n*128 + kt*32 + q*8);
    wgv[nt] = (n < CC) ? W_tg[n] : 0.f;
    bgv[nt] = (n < CC) ? b_tg[n] : 0.f;
  }
  for (int i = tid; i < 2*16*144; i += 256) ((unsigned short*)hls)[i] = 0;
  float xc[2][4], pc[2][4], cc[2][4];
  #pragma unroll
  for (int nt=0;nt<2;nt++){
    #pragma unroll
    for (int i=0;i<4;i++){
      size_t off = (size_t)(bbase + q*4 + i)*128 + col_[nt];
      xc[nt][i] = Xp[off]; pc[nt][i] = pre2[off]; cc[nt][i] = cq[off];
    }
  }
  __syncthreads();
  for (int t=0;t<TT;t++){
    const int p = t & 1;
    float xn[2][4], pn[2][4], cn[2][4];
    if (t < TT-1){
      #pragma unroll
      for (int nt=0;nt<2;nt++){
        #pragma unroll
        for (int i=0;i<4;i++){
          size_t off = ((size_t)(t+1)*BB + bbase + q*4 + i)*128 + col_[nt];
          xn[nt][i] = Xp[off]; pn[nt][i] = pre2[off]; cn[nt][i] = cq[off];
        }
      }
    }
    short8 af[4];
    #pragma unroll
    for (int kt=0;kt<4;kt++) af[kt] = *(const short8*)&hls[p][r16][kt*32 + q*8];
    floatx4 acc[2];
    #pragma unroll
    for (int nt=0;nt<2;nt++){ acc[nt][0]=xc[nt][0]; acc[nt][1]=xc[nt][1]; acc[nt][2]=xc[nt][2]; acc[nt][3]=xc[nt][3]; }
    #pragma unroll
    for (int kt=0;kt<4;kt++){
      #pragma unroll
      for (int nt=0;nt<2;nt++)
        acc[nt] = __builtin_amdgcn_mfma_f32_16x16x32_bf16(af[kt], bfr[nt][kt], acc[nt], 0,0,0);
    }
    #pragma unroll
    for (int nt=0;nt<2;nt++){
      float g = sigmoidf_((float)t*wgv[nt] + bgv[nt]);
      #pragma unroll
      for (int i=0;i<4;i++){
        float hv = tanhf(acc[nt][i]) * g;
        size_t off = ((size_t)t*BB + bbase + q*4 + i)*128 + col_[nt];
        x2abf[off] = f2bf(pc[nt][i] + cc[nt][i]*hv);
        hls[p^1][q*4 + i][col_[nt]] = f2bf(hv);
      }
    }
    if (t < TT-1){
      #pragma unroll
      for (int nt=0;nt<2;nt++){
        #pragma unroll
        for (int i=0;i<4;i++){ xc[nt][i]=xn[nt][i]; pc[nt][i]=pn[nt][i]; cc[nt][i]=cn[nt][i]; }
      }
    }
    __syncthreads();
  }
}

// ---------------------------------------------------------------------------
// k_rnn2_mfma: z=sig(Zx+h@Wzh^T); th=tanh(Hx+h@Whh2^T); h=(1-z)h+z*th
// Zx/Hx t-major; writes h bf16 into Abf[(b*39+t)*512 + col] (b-major).
__global__ __launch_bounds__(256) void k_rnn2_mfma(
    const float* __restrict__ Zx, const float* __restrict__ Hx,
    const unsigned short* __restrict__ Wzh, const unsigned short* __restrict__ Whh2,
    unsigned short* __restrict__ Abf)
{
  __shared__ __align__(16) unsigned short hls[2][16][144];
  const int tid = threadIdx.x, w = tid >> 6, l = tid & 63, q = l >> 4, r16 = l & 15;
  const int bbase = blockIdx.x*16;
  short8 bfz[2][4], bfh[2][4];
  int col_[2];
  #pragma unroll
  for (int nt=0;nt<2;nt++){
    int n = w*32 + nt*16 + r16; col_[nt] = n;
    #pragma unroll
    for (int kt=0;kt<4;kt++){
      bfz[nt][kt] = *(const short8*)(Wzh  + (size_t)n*128 + kt*32 + q*8);
      bfh[nt][kt] = *(const short8*)(Whh2 + (size_t)n*128 + kt*32 + q*8);
    }
  }
  for (int i = tid; i < 2*16*144; i += 256) ((unsigned short*)hls)[i] = 0;
  floatx4 hold[2];
  #pragma unroll
  for (int nt=0;nt<2;nt++){ hold[nt][0]=0.f; hold[nt][1]=0.f; hold[nt][2]=0.f; hold[nt][3]=0.f; }
  float zc[2][4], hc[2][4];
  #pragma unroll
  for (int nt=0;nt<2;nt++){
    #pragma unroll
    for (int i=0;i<4;i++){
      size_t off = (size_t)(bbase + q*4 + i)*128 + col_[nt];
      zc[nt][i] = Zx[off]; hc[nt][i] = Hx[off];
    }
  }
  __syncthreads();
  for (int t=0;t<TT;t++){
    const int p = t & 1;
    float zn[2][4], hn[2][4];
    if (t < TT-1){
      #pragma unroll
      for (int nt=0;nt<2;nt++){
        #pragma unroll
        for (int i=0;i<4;i++){
          size_t off = ((size_t)(t+1)*BB + bbase + q*4 + i)*128 + col_[nt];
          zn[nt][i] = Zx[off]; hn[nt][i] = Hx[off];
        }
      }
    }
    short8 af[4];
    #pragma unroll
    for (int kt=0;kt<4;kt++) af[kt] = *(const short8*)&hls[p][r16][kt*32 + q*8];
    floatx4 accz[2], acch[2];
    #pragma unroll
    for (int nt=0;nt<2;nt++){
      accz[nt][0]=zc[nt][0]; accz[nt][1]=zc[nt][1]; accz[nt][2]=zc[nt][2]; accz[nt][3]=zc[nt][3];
      acch[nt][0]=hc[nt][0]; acch[nt][1]=hc[nt][1]; acch[nt][2]=hc[nt][2]; acch[nt][3]=hc[nt][3];
    }
    #pragma unroll
    for (int kt=0;kt<4;kt++){
      #pragma unroll
      for (int nt=0;nt<2;nt++){
        accz[nt] = __builtin_amdgcn_mfma_f32_16x16x32_bf16(af[kt], bfz[nt][kt], accz[nt], 0,0,0);
        acch[nt] = __builtin_amdgcn_mfma_f32_16x16x32_bf16(af[kt], bfh[nt][kt], acch[nt], 0,0,0);
      }
    }
    #pragma unroll
    for (int nt=0;nt<2;nt++){
      #pragma unroll
      for (int i=0;i<4;i++){
        float z  = sigmoidf_(accz[nt][i]);
        float th = tanhf(acch[nt][i]);
        float hv = (1.f - z)*hold[nt][i] + z*th;
        hold[nt][i] = hv;
        unsigned short hb = f2bf(hv);
        if (col_[nt] < CC)
          Abf[((size_t)(bbase + q*4 + i)*TT + t)*512 + col_[nt]] = hb;
        hls[p^1][q*4 + i][col_[nt]] = hb;
      }
    }
    if (t < TT-1){
      #pragma unroll
      for (int nt=0;nt<2;nt++){
        #pragma unroll
        for (int i=0;i<4;i++){ zc[nt][i]=zn[nt][i]; hc[nt][i]=hn[nt][i]; }
      }
    }
    __syncthreads();
  }
}

// ---------------------------------------------------------------------------
// k_o1_mfma: o1bf[NRB][256] = bf16(sigmoid(Abf @ p1bf^T + p1_b))
__global__ __launch_bounds__(256) void k_o1_mfma(
    const unsigned short* __restrict__ Abf, const unsigned short* __restrict__ p1bf,
    const float* __restrict__ p1_b, unsigned short* __restrict__ o1bf)
{
  __shared__ __align__(16) unsigned short Asl[8][64][8];   // 8 KB
  __shared__ __align__(16) unsigned short Bsl[8][256][8];  // 32 KB
  const int tid = threadIdx.x;
  const int w = tid >> 6, l = tid & 63;
  const int q = l >> 4, r16 = l & 15;
  const int rTile = blockIdx.x * 64;
  floatx4 acc[4][4];
  #pragma unroll
  for (int a=0;a<4;a++){
    #pragma unroll
    for (int b=0;b<4;b++){ acc[a][b][0]=0.f; acc[a][b][1]=0.f; acc[a][b][2]=0.f; acc[a][b][3]=0.f; }
  }
  for (int c = 0; c < 8; c++){
    const int k0 = c*64;
    #pragma unroll
    for (int i=0;i<2;i++){
      int u = i*256 + tid; int seg = u>>6, m = u&63;
      gl_lds16(&Asl[seg][m][0], Abf + (size_t)(rTile+m)*512 + k0 + seg*8);
    }
    #pragma unroll
    for (int i=0;i<8;i++){
      int u = i*256 + tid; int seg = u>>8, n = u&255;
      gl_lds16(&Bsl[seg][n][0], p1bf + (size_t)n*512 + k0 + seg*8);
    }
    __syncthreads();
    #pragma unroll
    for (int ks=0; ks<2; ks++){
      int seg = ks*4 + q;
      short8 af[4], bfr[4];
      #pragma unroll
      for (int mt=0;mt<4;mt++) af[mt] = *(const short8*)&Asl[seg][mt*16 + r16][0];
      #pragma unroll
      for (int nt=0;nt<4;nt++) bfr[nt] = *(const short8*)&Bsl[seg][w*64 + nt*16 + r16][0];
      #pragma unroll
      for (int mt=0;mt<4;mt++){
        #pragma unroll
        for (int nt=0;nt<4;nt++)
          acc[mt][nt] = __builtin_amdgcn_mfma_f32_16x16x32_bf16(af[mt], bfr[nt], acc[mt][nt], 0,0,0);
      }
    }
    __syncthreads();
  }
  #pragma unroll
  for (int nt=0;nt<4;nt++){
    int col = w*64 + nt*16 + r16;
    float bb = p1_b[col];
    #pragma unroll
    for (int mt=0;mt<4;mt++){
      #pragma unroll
      for (int i=0;i<4;i++){
        int row = rTile + mt*16 + q*4 + i;
        o1bf[(size_t)row*256 + col] = f2bf(sigmoidf_(acc[mt][nt][i] + bb));
      }
    }
  }
}

// ---------------------------------------------------------------------------
// k_o2_mfma: o2 = sigmoid(o1bf @ p2bf^T + p2_b); out = sigmoid(o2 @ p3 + p3_b)
__global__ __launch_bounds__(256) void k_o2_mfma(
    const unsigned short* __restrict__ o1bf, const unsigned short* __restrict__ p2bf,
    const float* __restrict__ p2_b, const float* __restrict__ p3_W,
    const float* __restrict__ p3_b, float* __restrict__ out)
{
  __shared__ __align__(16) unsigned short Asl[8][64][8];   // 8 KB
  __shared__ __align__(16) unsigned short Bsl[8][128][8];  // 16 KB
  __shared__ float red[64][4];
  const int tid = threadIdx.x;
  const int w = tid >> 6, l = tid & 63;
  const int q = l >> 4, r16 = l & 15;
  const int rTile = blockIdx.x * 64;
  floatx4 acc[4][2];
  #pragma unroll
  for (int a=0;a<4;a++){
    #pragma unroll
    for (int b=0;b<2;b++){ acc[a][b][0]=0.f; acc[a][b][1]=0.f; acc[a][b][2]=0.f; acc[a][b][3]=0.f; }
  }
  for (int c = 0; c < 4; c++){
    const int k0 = c*64;
    #pragma unroll
    for (int i=0;i<2;i++){
      int u = i*256 + tid; int seg = u>>6, m = u&63;
      gl_lds16(&Asl[seg][m][0], o1bf + (size_t)(rTile+m)*256 + k0 + seg*8);
    }
    #pragma unroll
    for (int i=0;i<4;i++){
      int u = i*256 + tid; int seg = u>>7, n = u&127;
      gl_lds16(&Bsl[seg][n][0], p2bf + (size_t)n*256 + k0 + seg*8);
    }
    __syncthreads();
    #pragma unroll
    for (int ks=0; ks<2; ks++){
      int seg = ks*4 + q;
      short8 af[4], bfr[2];
      #pragma unroll
      for (int mt=0;mt<4;mt++) af[mt] = *(const short8*)&Asl[seg][mt*16 + r16][0];
      #pragma unroll
      for (int nt=0;nt<2;nt++) bfr[nt] = *(const short8*)&Bsl[seg][w*32 + nt*16 + r16][0];
      #pragma unroll
      for (int mt=0;mt<4;mt++){
        #pragma unroll
        for (int nt=0;nt<2;nt++)
          acc[mt][nt] = __builtin_amdgcn_mfma_f32_16x16x32_bf16(af[mt], bfr[nt], acc[mt][nt], 0,0,0);
      }
    }
    __syncthreads();
  }
  const int n0 = w*32 + r16, n1 = n0 + 16;
  const float pb0 = (n0<CC)? p2_b[n0]:0.f, pb1 = (n1<CC)? p2_b[n1]:0.f;
  const float p30 = (n0<CC)? p3_W[n0]:0.f, p31 = (n1<CC)? p3_W[n1]:0.f;
  #pragma unroll
  for (int mt=0;mt<4;mt++){
    #pragma unroll
    for (int i=0;i<4;i++){
      float s = sigmoidf_(acc[mt][0][i]+pb0)*p30 + sigmoidf_(acc[mt][1][i]+pb1)*p31;
      s += __shfl_xor(s,1,16); s += __shfl_xor(s,2,16);
      s += __shfl_xor(s,4,16); s += __shfl_xor(s,8,16);
      if (r16==0) red[mt*16 + q*4 + i][w] = s;
    }
  }
  __syncthreads();
  if (tid < 64){
    float o = red[tid][0]+red[tid][1]+red[tid][2]+red[tid][3] + p3_b[0];
    out[rTile + tid] = sigmoidf_(o);
  }
}

// ---------------------------------------------------------------------------
extern "C" void kernel_launch(void* const* d_in, const int* in_sizes, int n_in,
                              void* d_out, int out_size, void* d_ws, size_t ws_size,
                              hipStream_t stream) {
  const float* q_m       = (const float*)d_in[0];
  const float* q_m_next  = (const float*)d_in[1];
  const int*   s_id      = (const int*)d_in[3];
  const int*   e_id      = (const int*)d_in[4];
  const int*   r_idx     = (const int*)d_in[5];
  const int*   q_next    = (const int*)d_in[6];
  const float* emb_problem = (const float*)d_in[8];
  const float* student_W = (const float*)d_in[9];
  const float* k_diff_W  = (const float*)d_in[10];
  const float* e_disc_W  = (const float*)d_in[11];
  const float* answer_W  = (const float*)d_in[12];
  const float* zz_W      = (const float*)d_in[13];
  const float* zz_b      = (const float*)d_in[14];
  const float* d_t       = (const float*)d_in[15];
  const float* d_e       = (const float*)d_in[16];
  const float* W_ih      = (const float*)d_in[17];
  const float* b_ih      = (const float*)d_in[18];
  const float* W_hh      = (const float*)d_in[19];
  const float* W_tg      = (const float*)d_in[21];
  const float* b_tg      = (const float*)d_in[22];
  const float* W_z       = (const float*)d_in[23];
  const float* b_z       = (const float*)d_in[24];
  const float* W_h       = (const float*)d_in[25];
  const float* b_h       = (const float*)d_in[26];
  const float* p1_W      = (const float*)d_in[27];
  const float* p1_b      = (const float*)d_in[28];
  const float* p2_W      = (const float*)d_in[29];
  const float* p2_b      = (const float*)d_in[30];
  const float* p3_W      = (const float*)d_in[31];
  const float* p3_b      = (const float*)d_in[32];

  float* ws = (float*)d_ws;
  size_t o = 0;
  float* rtab = ws + o; o += 1024;
  float* BUF1 = ws + o; o += (size_t)NRB*128;   // AB -> Xp -> o1bf
  float* BUF2 = ws + o; o += (size_t)NRB*128;   // pre2 -> Zx
  float* BUF3 = ws + o; o += (size_t)NRB*128;   // cq -> Hx
  unsigned short* qbf   = (unsigned short*)(ws + o); o += (size_t)NRB*64;  // qbf -> x2abf
  unsigned short* x1abf = (unsigned short*)(ws + o); o += (size_t)NRB*64;
  unsigned short* Abf   = (unsigned short*)(ws + o); o += (size_t)NRB*256; // [NRB][512] ush
  unsigned short* wts   = (unsigned short*)(ws + o); o += 57344/2*2;       // 7*16384 ush = 57344 f32? no:
  // (7*16384 ush = 114688 ush = 57344 f32)
  o = o - 57344 + 57344;  // keep as is
  unsigned short* p1bf  = wts + 7*16384;
  unsigned short* p2bf  = p1bf + 256*512;
  unsigned short* x2abf = qbf;
  unsigned short* o1bf  = (unsigned short*)BUF1;

  const unsigned short* zzWbf   = wts + 0*16384;
  const unsigned short* Wih123  = wts + 1*16384;
  const unsigned short* Wz123   = wts + 2*16384;
  const unsigned short* Wh123   = wts + 3*16384;
  const unsigned short* Whhbf   = wts + 4*16384;
  const unsigned short* Wzhbf   = wts + 5*16384;
  const unsigned short* Whh2bf  = wts + 6*16384;

  hipLaunchKernelGGL(k_rcontrib, dim3(6), dim3(128), 0, stream,
                     W_ih, W_z, W_h, answer_W, rtab);
  hipLaunchKernelGGL(k_convW, dim3(1088), dim3(256), 0, stream,
                     zz_W, W_ih, W_z, W_h, W_hh, p1_W, p2_W, wts, p1bf, p2bf);
  hipLaunchKernelGGL(k_hcat, dim3(2048), dim3(256), 0, stream,
                     emb_problem, q_next, q_m_next, Abf);
  hipLaunchKernelGGL(k_cast, dim3(2048), dim3(256), 0, stream, q_m, qbf);
  hipLaunchKernelGGL(k_bgemm, dim3(NRB/64), dim3(256), 0, stream,
                     qbf, zzWbf, zz_b, rtab, 0, r_idx, BUF1);               // AB
  hipLaunchKernelGGL(k_elem1, dim3(2048), dim3(256), 0, stream,
                     BUF1, q_m, s_id, e_id, student_W, k_diff_W, e_disc_W,
                     d_t, d_e, x1abf, BUF2, BUF3);                          // x1abf, pre2, cq
  hipLaunchKernelGGL(k_bgemm, dim3(NRB/64), dim3(256), 0, stream,
                     x1abf, Wih123, b_ih, rtab, 1, r_idx, BUF1);            // Xp
  hipLaunchKernelGGL(k_rnn1_mfma, dim3(BB/16), dim3(256), 0, stream,
                     BUF1, BUF2, BUF3, Whhbf, W_tg, b_tg, x2abf);           // x2abf
  hipLaunchKernelGGL(k_bgemm, dim3(NRB/64), dim3(256), 0, stream,
                     x2abf, Wz123, b_z, rtab + 256, 1, r_idx, BUF2);        // Zx
  hipLaunchKernelGGL(k_bgemm, dim3(NRB/64), dim3(256), 0, stream,
                     x2abf, Wh123, b_h, rtab + 512, 1, r_idx, BUF3);        // Hx
  hipLaunchKernelGGL(k_rnn2_mfma, dim3(BB/16), dim3(256), 0, stream,
                     BUF2, BUF3, Wzhbf, Whh2bf, Abf);                       // out2 -> Abf[:, :123]
  hipLaunchKernelGGL(k_o1_mfma, dim3(NRB/64), dim3(256), 0, stream,
                     Abf, p1bf, p1_b, o1bf);
  hipLaunchKernelGGL(k_o2_mfma, dim3(NRB/64), dim3(256), 0, stream,
                     o1bf, p2bf, p2_b, p3_W, p3_b, (float*)d_out);
}

// Round 4
// 420.464 us; speedup vs baseline: 4.6517x; 1.2461x over previous
//
#include <hip/hip_runtime.h>
#include <hip/hip_bf16.h>

#define NRB 39936   // B*T = 1024*39
#define BB 1024
#define TT 39
#define CC 123      // NUM_C == H
#define EMBD 256
#define PCH 136     // padded LDS row pitch (ush) -> 2-way bank aliasing only (free)

typedef __attribute__((ext_vector_type(8))) short short8;
typedef __attribute__((ext_vector_type(4))) float floatx4;
typedef unsigned short us;

__device__ __forceinline__ float rcp_(float x){ return __builtin_amdgcn_rcpf(x); }
__device__ __forceinline__ float fsig(float x){ return rcp_(1.f + __expf(-x)); }
__device__ __forceinline__ float ftanh(float x){
  float ax = __builtin_fabsf(x);
  float e = __expf(-2.f*ax);
  float r = (1.f - e) * rcp_(1.f + e);
  return __builtin_copysignf(r, x);
}
__device__ __forceinline__ us f2bf(float x){
  union { float f; unsigned u; } v; v.f = x;
  unsigned r = v.u + 0x7FFFu + ((v.u >> 16) & 1u);
  return (us)(r >> 16);
}
__device__ __forceinline__ float bf2f(us u){
  union { unsigned u; float f; } v; v.u = ((unsigned)u) << 16; return v.f;
}

// async global->LDS, 16B per lane; LDS dest = wave-uniform base + lane*16
__device__ __forceinline__ void gl_lds16(void* lds, const void* g){
  __builtin_amdgcn_global_load_lds(
      (const __attribute__((address_space(1))) unsigned int*)g,
      (__attribute__((address_space(3))) unsigned int*)lds, 16, 0, 0);
}

// ---------------------------------------------------------------------------
// k_pre: fused preprocessing, block-range dispatch.
//  region 0 (6 blocks):    rtab[(which*2+r)*128+h] = W[h][123:]·answer_W[r]
//  region 1 (1088 blocks): convW -> 7x[128][128] bf16 wts + p1bf(permuted) + p2bf
//  region 2 (2496 blocks): qbf[t][b][128] bf16 from q_m[b][t][123]
//  region 3 (1872 blocks): Abf cols [0,384): [emb(256) | qmn(123) | 0(5)]
#define G_RC 6
#define G_CW 1088
#define G_CAST 2496
#define G_HCAT 1872
#define G_PRE (G_RC + G_CW + G_CAST + G_HCAT)

__global__ __launch_bounds__(256) void k_pre(
    const float* __restrict__ W_ih, const float* __restrict__ W_z,
    const float* __restrict__ W_h, const float* __restrict__ answer_W,
    const float* __restrict__ zz_W, const float* __restrict__ W_hh,
    const float* __restrict__ p1_W, const float* __restrict__ p2_W,
    const float* __restrict__ emb, const int* __restrict__ q_next,
    const float* __restrict__ qmn, const float* __restrict__ q_m,
    float* __restrict__ rtab, us* __restrict__ wts,
    us* __restrict__ p1bf, us* __restrict__ p2bf,
    us* __restrict__ qbf, us* __restrict__ Abf)
{
  const int blk = blockIdx.x, tid = threadIdx.x;
  if (blk < G_RC){
    int which = blk >> 1, j = blk & 1, h = tid;
    if (h >= CC) return;
    const float* W; int stride;
    if (which==0){ W=W_ih; stride=379; } else if (which==1){ W=W_z; stride=502; } else { W=W_h; stride=502; }
    const float* a = answer_W + j*EMBD;
    const float* w = W + (size_t)h*stride + CC;
    float acc = 0.f;
    #pragma unroll 8
    for (int i=0;i<EMBD;i++) acc += w[i]*a[i];
    rtab[(which*2+j)*128 + h] = acc;
    return;
  }
  if (blk < G_RC + G_CW){
    int i = (blk - G_RC)*256 + tid;
    if (i < 7*16384){
      int w = i >> 14, idx = i & 16383, n = idx >> 7, k = idx & 127;
      float v = 0.f;
      if (n < CC && k < CC){
        if      (w==0) v = zz_W[n*CC + k];
        else if (w==1) v = W_ih[n*379 + k];
        else if (w==2) v = W_z [n*502 + k];
        else if (w==3) v = W_h [n*502 + k];
        else if (w==4) v = W_hh[n*CC + k];
        else if (w==5) v = W_z [n*502 + 379 + k];
        else           v = W_h [n*502 + 379 + k];
      }
      wts[i] = f2bf(v);
      return;
    }
    int j = i - 7*16384;
    if (j < 256*512){
      int n = j >> 9, k = j & 511;
      float v;
      if      (k < 379) v = p1_W[n*502 + k + 123];   // emb|qmn block (orig cols 123..501)
      else if (k < 384) v = 0.f;
      else if (k < 507) v = p1_W[n*502 + (k - 384)]; // out2 block (orig cols 0..122)
      else              v = 0.f;
      p1bf[j] = f2bf(v);
      return;
    }
    j -= 256*512;
    if (j < 128*256){
      int n = j >> 8, k = j & 255;
      p2bf[j] = f2bf(n < CC ? p2_W[n*256 + k] : 0.f);
    }
    return;
  }
  if (blk < G_RC + G_CW + G_CAST){
    const size_t total = (size_t)NRB*128;
    for (size_t i = (size_t)(blk - G_RC - G_CW)*256 + tid; i < total; i += (size_t)G_CAST*256){
      int col = (int)(i & 127); size_t rp = i >> 7;
      int t = (int)(rp >> 10), b = (int)(rp & 1023);
      float v = (col < CC) ? q_m[((size_t)b*TT + t)*CC + col] : 0.f;
      qbf[i] = f2bf(v);
    }
    return;
  }
  // hcat region: chunks of 8 cols, cols [0,384)
  {
    const size_t nchunk = (size_t)NRB*48;
    for (size_t c = (size_t)(blk - G_RC - G_CW - G_CAST)*256 + tid; c < nchunk; c += (size_t)G_HCAT*256){
      size_t row = c / 48;
      int c0 = (int)(c - row*48) * 8;
      short8 o;
      if (c0 < 256){
        int qn = q_next[row];
        float4 v0 = *(const float4*)(emb + (size_t)qn*EMBD + c0);
        float4 v1 = *(const float4*)(emb + (size_t)qn*EMBD + c0 + 4);
        o[0]=f2bf(v0.x); o[1]=f2bf(v0.y); o[2]=f2bf(v0.z); o[3]=f2bf(v0.w);
        o[4]=f2bf(v1.x); o[5]=f2bf(v1.y); o[6]=f2bf(v1.z); o[7]=f2bf(v1.w);
      } else {
        int j0 = c0 - 256;
        #pragma unroll
        for (int jj=0;jj<8;jj++){
          int j = j0 + jj;
          o[jj] = (j < CC) ? f2bf(qmn[row*CC + j]) : (short)0;
        }
      }
      *(short8*)(Abf + row*512 + c0) = o;
    }
  }
}

// ---------------------------------------------------------------------------
// k_zz_elem: AB = qbf @ zzW^T + zz_b (MFMA); epilogue computes & writes swizzled
//  x1a_swz (A-frag order), pre2_swz / cq_swz (C-frag order), all bf16.
__global__ __launch_bounds__(256) void k_zz_elem(
    const us* __restrict__ X, const us* __restrict__ W,
    const float* __restrict__ zz_b,
    const float* __restrict__ q_m, const int* __restrict__ s_id,
    const int* __restrict__ e_id, const float* __restrict__ student_W,
    const float* __restrict__ k_diff_W, const float* __restrict__ e_disc_W,
    const float* __restrict__ d_t_p, const float* __restrict__ d_e_p,
    us* __restrict__ x1a, us* __restrict__ pre2, us* __restrict__ cqb)
{
  __shared__ __align__(16) us Asl[16][64][8];   // 16 KB
  const int tid = threadIdx.x, w = tid >> 6, l = tid & 63, q = l >> 4, r16 = l & 15;
  const int rTile = blockIdx.x*64;
  short8 bfr[2][4];
  #pragma unroll
  for (int nt=0;nt<2;nt++){
    int n = w*32 + nt*16 + r16;
    #pragma unroll
    for (int kt=0;kt<4;kt++)
      bfr[nt][kt] = *(const short8*)(W + (size_t)n*128 + kt*32 + q*8);
  }
  #pragma unroll
  for (int i=0;i<4;i++){
    int seg = i*4 + w;
    gl_lds16(&Asl[seg][l][0], X + (size_t)(rTile+l)*128 + seg*8);
  }
  floatx4 acc[4][2];
  #pragma unroll
  for (int mt=0;mt<4;mt++){
    #pragma unroll
    for (int nt=0;nt<2;nt++){ acc[mt][nt][0]=0.f; acc[mt][nt][1]=0.f; acc[mt][nt][2]=0.f; acc[mt][nt][3]=0.f; }
  }
  __syncthreads();
  #pragma unroll
  for (int kt=0;kt<4;kt++){
    short8 af[4];
    #pragma unroll
    for (int mt=0;mt<4;mt++) af[mt] = *(const short8*)&Asl[kt*4+q][mt*16+r16][0];
    #pragma unroll
    for (int mt=0;mt<4;mt++){
      #pragma unroll
      for (int nt=0;nt<2;nt++)
        acc[mt][nt] = __builtin_amdgcn_mfma_f32_16x16x32_bf16(af[mt], bfr[nt][kt], acc[mt][nt], 0,0,0);
    }
  }
  const float dt = d_t_p[0], de = d_e_p[0];
  float zzb[2]; int colv[2];
  #pragma unroll
  for (int nt=0;nt<2;nt++){
    int col = w*32 + nt*16 + r16; colv[nt] = col;
    zzb[nt] = (col < CC) ? zz_b[col] : 0.f;
  }
  const int t = rTile >> 10;           // rows of this block share t (1024 % 64 == 0)
  #pragma unroll
  for (int mt=0;mt<4;mt++){
    #pragma unroll
    for (int i=0;i<4;i++){
      int row = rTile + mt*16 + q*4 + i;
      int b = row & 1023;
      int g = b*TT + t;
      int btile = b >> 4, r = b & 15;
      int sid = s_id[b];
      int e   = e_id[g];
      float ed = fsig(e_disc_W[e]) * de;
      size_t base = ((size_t)t*64 + btile)*2048;
      #pragma unroll
      for (int nt=0;nt<2;nt++){
        int col = colv[nt];
        float x1v = 0.f, p2v = 0.f, cqv = 0.f;
        if (col < CC){
          float ab = acc[mt][nt][i] + zzb[nt];
          float sp = fsig(student_W[(size_t)sid*CC + col]);
          float kd = fsig(k_diff_W[(size_t)e*CC + col]);
          float qv = q_m[(size_t)g*CC + col];
          x1v = ab*sp;
          p2v = ed*(dt*sp - kd)*qv;
          cqv = ed*(1.f - dt)*qv;
        }
        // x1a: A-frag order: chunk = (col>>5)*64 + ((col>>3)&3)*16 + r, pos = col&7
        x1a[base + (size_t)(((col>>5)*64 + ((col>>3)&3)*16 + r)*8) + (col&7)] = f2bf(x1v);
        // pre2/cq: C-frag order: chunk = (col>>5)*64 + (r>>2)*16 + (col&15), pos = ((col>>4)&1)*4 + (r&3)
        size_t off = base + (size_t)(((col>>5)*64 + ((r>>2))*16 + (col&15))*8) + ((col>>4)&1)*4 + (r&3);
        pre2[off] = f2bf(p2v);
        cqb[off]  = f2bf(cqv);
      }
    }
  }
}

// ---------------------------------------------------------------------------
// k_mid: fused rnn1 + (Zx,Hx) + rnn2. 64 blocks x 16 batch rows.
// Per step: Xp = x1a@Wih + b_ih + rtab1[r]; h1 = tanh(Xp + h1@Whh)*g(t);
//           x2a = pre2 + cq*h1 (LDS round-trip to A-layout);
//           az = b_z + rtab2[r] + x2a@Wzx + h2@Wzh; ah likewise;
//           h2 = (1-sig(az))*h2 + sig(az)*tanh(ah); ring-buffered, dumped /4 steps.
__global__ __launch_bounds__(256,1) void k_mid(
    const us* __restrict__ x1a, const us* __restrict__ pre2, const us* __restrict__ cqb,
    const us* __restrict__ Wih, const us* __restrict__ Whh,
    const us* __restrict__ Wzx, const us* __restrict__ Whx,
    const us* __restrict__ Wzh, const us* __restrict__ Whh2,
    const float* __restrict__ b_ih, const float* __restrict__ b_z, const float* __restrict__ b_h,
    const float* __restrict__ W_tg, const float* __restrict__ b_tg,
    const float* __restrict__ rtab, const int* __restrict__ r_idx,
    us* __restrict__ Abf)
{
  __shared__ __align__(16) us x1s[2][2048];
  __shared__ __align__(16) us p2s[2][2048];
  __shared__ __align__(16) us cqs[2][2048];
  __shared__ __align__(16) us h1s[2][16*PCH];
  __shared__ __align__(16) us x2s[16*PCH];
  __shared__ __align__(16) us h2r[4][16*PCH];
  __shared__ int rint[640];
  const int tid = threadIdx.x, w = tid >> 6, l = tid & 63, q = l >> 4, r16 = l & 15;
  const int bbase = blockIdx.x*16;

  short8 fih[2][4], fhh[2][4], fzx[2][4], fhx[2][4], fzh[2][4], fh2[2][4];
  float bih[2], bz[2], bh[2], wgv[2], bgv[2];
  float r1v[2][2], r2v[2][2], r3v[2][2];
  int colv[2];
  #pragma unroll
  for (int nt=0;nt<2;nt++){
    int n = w*32 + nt*16 + r16; colv[nt] = n;
    #pragma unroll
    for (int kt=0;kt<4;kt++){
      fih[nt][kt] = *(const short8*)(Wih  + (size_t)n*128 + kt*32 + q*8);
      fhh[nt][kt] = *(const short8*)(Whh  + (size_t)n*128 + kt*32 + q*8);
      fzx[nt][kt] = *(const short8*)(Wzx  + (size_t)n*128 + kt*32 + q*8);
      fhx[nt][kt] = *(const short8*)(Whx  + (size_t)n*128 + kt*32 + q*8);
      fzh[nt][kt] = *(const short8*)(Wzh  + (size_t)n*128 + kt*32 + q*8);
      fh2[nt][kt] = *(const short8*)(Whh2 + (size_t)n*128 + kt*32 + q*8);
    }
    bool v = n < CC;
    bih[nt] = v ? b_ih[n] : 0.f;
    bz [nt] = v ? b_z [n] : 0.f;
    bh [nt] = v ? b_h [n] : 0.f;
    wgv[nt] = v ? W_tg[n] : 0.f;
    bgv[nt] = v ? b_tg[n] : 0.f;
    r1v[0][nt] = v ? rtab[0*128+n] : 0.f;  r1v[1][nt] = v ? rtab[1*128+n] : 0.f;
    r2v[0][nt] = v ? rtab[2*128+n] : 0.f;  r2v[1][nt] = v ? rtab[3*128+n] : 0.f;
    r3v[0][nt] = v ? rtab[4*128+n] : 0.f;  r3v[1][nt] = v ? rtab[5*128+n] : 0.f;
  }
  for (int i = tid; i < TT*16; i += 256){
    int t = i >> 4, row = i & 15;
    rint[i] = r_idx[(size_t)(bbase+row)*TT + t];
  }
  for (int i = tid; i < 16*PCH; i += 256){ h1s[0][i] = 0; h2r[3][i] = 0; }
  {
    size_t base = (size_t)blockIdx.x*2048;   // t=0 tile
    gl_lds16(&x1s[0][tid*8], x1a  + base + tid*8);
    gl_lds16(&p2s[0][tid*8], pre2 + base + tid*8);
    gl_lds16(&cqs[0][tid*8], cqb  + base + tid*8);
  }
  floatx4 hold[2];
  #pragma unroll
  for (int nt=0;nt<2;nt++){ hold[nt][0]=0.f; hold[nt][1]=0.f; hold[nt][2]=0.f; hold[nt][3]=0.f; }
  __syncthreads();

  for (int t=0; t<TT; t++){
    const int cur = t & 1, nxt = cur ^ 1, rb1 = t & 1, wb1 = rb1 ^ 1;
    if (t < TT-1){
      size_t base = ((size_t)(t+1)*64 + blockIdx.x)*2048;
      gl_lds16(&x1s[nxt][tid*8], x1a  + base + tid*8);
      gl_lds16(&p2s[nxt][tid*8], pre2 + base + tid*8);
      gl_lds16(&cqs[nxt][tid*8], cqb  + base + tid*8);
    }
    short8 a1[4], ah[4], a2p[4];
    #pragma unroll
    for (int kt=0;kt<4;kt++){
      a1[kt]  = *(const short8*)&x1s[cur][(kt*64 + l)*8];
      ah[kt]  = *(const short8*)&h1s[rb1][r16*PCH + kt*32 + q*8];
      a2p[kt] = *(const short8*)&h2r[(t+3)&3][r16*PCH + kt*32 + q*8];
    }
    short8 pc8 = *(const short8*)&p2s[cur][(w*64 + l)*8];
    short8 cc8 = *(const short8*)&cqs[cur][(w*64 + l)*8];
    int rs[4];
    #pragma unroll
    for (int i=0;i<4;i++) rs[i] = rint[t*16 + q*4 + i];
    floatx4 acc1[2], az[2], ahh[2];
    #pragma unroll
    for (int nt=0;nt<2;nt++){
      #pragma unroll
      for (int i=0;i<4;i++){
        acc1[nt][i] = bih[nt] + (rs[i] ? r1v[1][nt] : r1v[0][nt]);
        az  [nt][i] = bz [nt] + (rs[i] ? r2v[1][nt] : r2v[0][nt]);
        ahh [nt][i] = bh [nt] + (rs[i] ? r3v[1][nt] : r3v[0][nt]);
      }
    }
    #pragma unroll
    for (int kt=0;kt<4;kt++){
      #pragma unroll
      for (int nt=0;nt<2;nt++){
        acc1[nt] = __builtin_amdgcn_mfma_f32_16x16x32_bf16(a1[kt],  fih[nt][kt], acc1[nt], 0,0,0);
        acc1[nt] = __builtin_amdgcn_mfma_f32_16x16x32_bf16(ah[kt],  fhh[nt][kt], acc1[nt], 0,0,0);
        az [nt]  = __builtin_amdgcn_mfma_f32_16x16x32_bf16(a2p[kt], fzh[nt][kt], az [nt], 0,0,0);
        ahh[nt]  = __builtin_amdgcn_mfma_f32_16x16x32_bf16(a2p[kt], fh2[nt][kt], ahh[nt], 0,0,0);
      }
    }
    #pragma unroll
    for (int nt=0;nt<2;nt++){
      float g = fsig((float)t*wgv[nt] + bgv[nt]);
      #pragma unroll
      for (int i=0;i<4;i++){
        float h1 = ftanh(acc1[nt][i]) * g;
        h1s[wb1][(q*4+i)*PCH + colv[nt]] = f2bf(h1);
        float pcv = bf2f((us)pc8[nt*4+i]);
        float ccv = bf2f((us)cc8[nt*4+i]);
        x2s[(q*4+i)*PCH + colv[nt]] = f2bf(pcv + ccv*h1);
      }
    }
    __syncthreads();
    short8 ax2[4];
    #pragma unroll
    for (int kt=0;kt<4;kt++) ax2[kt] = *(const short8*)&x2s[r16*PCH + kt*32 + q*8];
    #pragma unroll
    for (int kt=0;kt<4;kt++){
      #pragma unroll
      for (int nt=0;nt<2;nt++){
        az [nt] = __builtin_amdgcn_mfma_f32_16x16x32_bf16(ax2[kt], fzx[nt][kt], az [nt], 0,0,0);
        ahh[nt] = __builtin_amdgcn_mfma_f32_16x16x32_bf16(ax2[kt], fhx[nt][kt], ahh[nt], 0,0,0);
      }
    }
    #pragma unroll
    for (int nt=0;nt<2;nt++){
      #pragma unroll
      for (int i=0;i<4;i++){
        float z  = fsig(az[nt][i]);
        float th = ftanh(ahh[nt][i]);
        float hv = hold[nt][i] + z*(th - hold[nt][i]);
        hold[nt][i] = hv;
        h2r[t&3][(q*4+i)*PCH + colv[nt]] = f2bf(hv);
      }
    }
    __syncthreads();
    if ((t & 3) == 3 || t == TT-1){
      int ns = (t & 3) + 1;
      int r = tid >> 4, c8 = tid & 15;
      for (int s=0; s<ns; s++){
        int td = t - (t & 3) + s;
        short8 vch = *(const short8*)&h2r[s][r*PCH + c8*8];
        *(short8*)(Abf + ((size_t)(bbase + r)*TT + td)*512 + 384 + c8*8) = vch;
      }
      __syncthreads();
    }
  }
}

// ---------------------------------------------------------------------------
// k_o1_mfma: o1bf[NRB][256] = bf16(sigmoid(Abf @ p1bf^T + p1_b))
__global__ __launch_bounds__(256) void k_o1_mfma(
    const us* __restrict__ Abf, const us* __restrict__ p1bf,
    const float* __restrict__ p1_b, us* __restrict__ o1bf)
{
  __shared__ __align__(16) us Asl[8][64][8];   // 8 KB
  __shared__ __align__(16) us Bsl[8][256][8];  // 32 KB
  const int tid = threadIdx.x;
  const int w = tid >> 6, l = tid & 63;
  const int q = l >> 4, r16 = l & 15;
  const int rTile = blockIdx.x * 64;
  floatx4 acc[4][4];
  #pragma unroll
  for (int a=0;a<4;a++){
    #pragma unroll
    for (int b=0;b<4;b++){ acc[a][b][0]=0.f; acc[a][b][1]=0.f; acc[a][b][2]=0.f; acc[a][b][3]=0.f; }
  }
  for (int c = 0; c < 8; c++){
    const int k0 = c*64;
    #pragma unroll
    for (int i=0;i<2;i++){
      int u = i*256 + tid; int seg = u>>6, m = u&63;
      gl_lds16(&Asl[seg][m][0], Abf + (size_t)(rTile+m)*512 + k0 + seg*8);
    }
    #pragma unroll
    for (int i=0;i<8;i++){
      int u = i*256 + tid; int seg = u>>8, n = u&255;
      gl_lds16(&Bsl[seg][n][0], p1bf + (size_t)n*512 + k0 + seg*8);
    }
    __syncthreads();
    #pragma unroll
    for (int ks=0; ks<2; ks++){
      int seg = ks*4 + q;
      short8 af[4], bfr[4];
      #pragma unroll
      for (int mt=0;mt<4;mt++) af[mt] = *(const short8*)&Asl[seg][mt*16 + r16][0];
      #pragma unroll
      for (int nt=0;nt<4;nt++) bfr[nt] = *(const short8*)&Bsl[seg][w*64 + nt*16 + r16][0];
      #pragma unroll
      for (int mt=0;mt<4;mt++){
        #pragma unroll
        for (int nt=0;nt<4;nt++)
          acc[mt][nt] = __builtin_amdgcn_mfma_f32_16x16x32_bf16(af[mt], bfr[nt], acc[mt][nt], 0,0,0);
      }
    }
    __syncthreads();
  }
  #pragma unroll
  for (int nt=0;nt<4;nt++){
    int col = w*64 + nt*16 + r16;
    float bb = p1_b[col];
    #pragma unroll
    for (int mt=0;mt<4;mt++){
      #pragma unroll
      for (int i=0;i<4;i++){
        int row = rTile + mt*16 + q*4 + i;
        o1bf[(size_t)row*256 + col] = f2bf(fsig(acc[mt][nt][i] + bb));
      }
    }
  }
}

// ---------------------------------------------------------------------------
// k_o2_mfma: o2 = sigmoid(o1bf @ p2bf^T + p2_b); out = sigmoid(o2 @ p3 + p3_b)
__global__ __launch_bounds__(256) void k_o2_mfma(
    const us* __restrict__ o1bf, const us* __restrict__ p2bf,
    const float* __restrict__ p2_b, const float* __restrict__ p3_W,
    const float* __restrict__ p3_b, float* __restrict__ out)
{
  __shared__ __align__(16) us Asl[8][64][8];   // 8 KB
  __shared__ __align__(16) us Bsl[8][128][8];  // 16 KB
  __shared__ float red[64][4];
  const int tid = threadIdx.x;
  const int w = tid >> 6, l = tid & 63;
  const int q = l >> 4, r16 = l & 15;
  const int rTile = blockIdx.x * 64;
  floatx4 acc[4][2];
  #pragma unroll
  for (int a=0;a<4;a++){
    #pragma unroll
    for (int b=0;b<2;b++){ acc[a][b][0]=0.f; acc[a][b][1]=0.f; acc[a][b][2]=0.f; acc[a][b][3]=0.f; }
  }
  for (int c = 0; c < 4; c++){
    const int k0 = c*64;
    #pragma unroll
    for (int i=0;i<2;i++){
      int u = i*256 + tid; int seg = u>>6, m = u&63;
      gl_lds16(&Asl[seg][m][0], o1bf + (size_t)(rTile+m)*256 + k0 + seg*8);
    }
    #pragma unroll
    for (int i=0;i<4;i++){
      int u = i*256 + tid; int seg = u>>7, n = u&127;
      gl_lds16(&Bsl[seg][n][0], p2bf + (size_t)n*256 + k0 + seg*8);
    }
    __syncthreads();
    #pragma unroll
    for (int ks=0; ks<2; ks++){
      int seg = ks*4 + q;
      short8 af[4], bfr[2];
      #pragma unroll
      for (int mt=0;mt<4;mt++) af[mt] = *(const short8*)&Asl[seg][mt*16 + r16][0];
      #pragma unroll
      for (int nt=0;nt<2;nt++) bfr[nt] = *(const short8*)&Bsl[seg][w*32 + nt*16 + r16][0];
      #pragma unroll
      for (int mt=0;mt<4;mt++){
        #pragma unroll
        for (int nt=0;nt<2;nt++)
          acc[mt][nt] = __builtin_amdgcn_mfma_f32_16x16x32_bf16(af[mt], bfr[nt], acc[mt][nt], 0,0,0);
      }
    }
    __syncthreads();
  }
  const int n0 = w*32 + r16, n1 = n0 + 16;
  const float pb0 = (n0<CC)? p2_b[n0]:0.f, pb1 = (n1<CC)? p2_b[n1]:0.f;
  const float p30 = (n0<CC)? p3_W[n0]:0.f, p31 = (n1<CC)? p3_W[n1]:0.f;
  #pragma unroll
  for (int mt=0;mt<4;mt++){
    #pragma unroll
    for (int i=0;i<4;i++){
      float s = fsig(acc[mt][0][i]+pb0)*p30 + fsig(acc[mt][1][i]+pb1)*p31;
      s += __shfl_xor(s,1,16); s += __shfl_xor(s,2,16);
      s += __shfl_xor(s,4,16); s += __shfl_xor(s,8,16);
      if (r16==0) red[mt*16 + q*4 + i][w] = s;
    }
  }
  __syncthreads();
  if (tid < 64){
    float o = red[tid][0]+red[tid][1]+red[tid][2]+red[tid][3] + p3_b[0];
    out[rTile + tid] = fsig(o);
  }
}

// ---------------------------------------------------------------------------
extern "C" void kernel_launch(void* const* d_in, const int* in_sizes, int n_in,
                              void* d_out, int out_size, void* d_ws, size_t ws_size,
                              hipStream_t stream) {
  const float* q_m       = (const float*)d_in[0];
  const float* q_m_next  = (const float*)d_in[1];
  const int*   s_id      = (const int*)d_in[3];
  const int*   e_id      = (const int*)d_in[4];
  const int*   r_idx     = (const int*)d_in[5];
  const int*   q_next    = (const int*)d_in[6];
  const float* emb_problem = (const float*)d_in[8];
  const float* student_W = (const float*)d_in[9];
  const float* k_diff_W  = (const float*)d_in[10];
  const float* e_disc_W  = (const float*)d_in[11];
  const float* answer_W  = (const float*)d_in[12];
  const float* zz_W      = (const float*)d_in[13];
  const float* zz_b      = (const float*)d_in[14];
  const float* d_t       = (const float*)d_in[15];
  const float* d_e       = (const float*)d_in[16];
  const float* W_ih      = (const float*)d_in[17];
  const float* b_ih      = (const float*)d_in[18];
  const float* W_hh      = (const float*)d_in[19];
  const float* W_tg      = (const float*)d_in[21];
  const float* b_tg      = (const float*)d_in[22];
  const float* W_z       = (const float*)d_in[23];
  const float* b_z       = (const float*)d_in[24];
  const float* W_h       = (const float*)d_in[25];
  const float* b_h       = (const float*)d_in[26];
  const float* p1_W      = (const float*)d_in[27];
  const float* p1_b      = (const float*)d_in[28];
  const float* p2_W      = (const float*)d_in[29];
  const float* p2_b      = (const float*)d_in[30];
  const float* p3_W      = (const float*)d_in[31];
  const float* p3_b      = (const float*)d_in[32];

  float* ws   = (float*)d_ws;
  float* rtab = ws;                                   // 1024 f32
  us* qbf  = (us*)(ws + 1024);                        // [NRB][128]
  us* x1a  = qbf  + (size_t)NRB*128;                  // swizzled [t][btile][2048]
  us* pre2 = x1a  + (size_t)NRB*128;
  us* cqb  = pre2 + (size_t)NRB*128;
  us* Abf  = cqb  + (size_t)NRB*128;                  // [NRB][512]
  us* o1bf = Abf  + (size_t)NRB*512;                  // [NRB][256]
  us* wts  = o1bf + (size_t)NRB*256;                  // 7*[128][128]
  us* p1bf = wts  + 7*16384;                          // [256][512]
  us* p2bf = p1bf + 256*512;                          // [128][256]

  const us* zzWbf  = wts + 0*16384;
  const us* Wih123 = wts + 1*16384;
  const us* Wz123  = wts + 2*16384;
  const us* Wh123  = wts + 3*16384;
  const us* Whhbf  = wts + 4*16384;
  const us* Wzhbf  = wts + 5*16384;
  const us* Whh2bf = wts + 6*16384;

  hipLaunchKernelGGL(k_pre, dim3(G_PRE), dim3(256), 0, stream,
                     W_ih, W_z, W_h, answer_W, zz_W, W_hh, p1_W, p2_W,
                     emb_problem, q_next, q_m_next, q_m,
                     rtab, wts, p1bf, p2bf, qbf, Abf);
  hipLaunchKernelGGL(k_zz_elem, dim3(NRB/64), dim3(256), 0, stream,
                     qbf, zzWbf, zz_b, q_m, s_id, e_id, student_W, k_diff_W,
                     e_disc_W, d_t, d_e, x1a, pre2, cqb);
  hipLaunchKernelGGL(k_mid, dim3(BB/16), dim3(256), 0, stream,
                     x1a, pre2, cqb, Wih123, Whhbf, Wz123, Wh123, Wzhbf, Whh2bf,
                     b_ih, b_z, b_h, W_tg, b_tg, rtab, r_idx, Abf);
  hipLaunchKernelGGL(k_o1_mfma, dim3(NRB/64), dim3(256), 0, stream,
                     Abf, p1bf, p1_b, o1bf);
  hipLaunchKernelGGL(k_o2_mfma, dim3(NRB/64), dim3(256), 0, stream,
                     o1bf, p2bf, p2_b, p3_W, p3_b, (float*)d_out);
}

// Round 5
// 380.110 us; speedup vs baseline: 5.1456x; 1.1062x over previous
//
#include <hip/hip_runtime.h>
#include <hip/hip_bf16.h>

#define NRB 39936   // B*T = 1024*39
#define BB 1024
#define TT 39
#define CC 123      // NUM_C == H
#define EMBD 256
#define PCH 136     // LDS row pitch (ush); 272B = 17*16 -> b128-aligned rows

typedef __attribute__((ext_vector_type(8))) short short8;
typedef __attribute__((ext_vector_type(4))) short shortv4;
typedef __attribute__((ext_vector_type(4))) float floatx4;
typedef unsigned short us;

__device__ __forceinline__ float rcp_(float x){ return __builtin_amdgcn_rcpf(x); }
__device__ __forceinline__ float fsig(float x){ return rcp_(1.f + __expf(-x)); }
__device__ __forceinline__ float ftanh(float x){
  float ax = __builtin_fabsf(x);
  float e = __expf(-2.f*ax);
  float r = (1.f - e) * rcp_(1.f + e);
  return __builtin_copysignf(r, x);
}
__device__ __forceinline__ us f2bf(float x){
  union { float f; unsigned u; } v; v.f = x;
  unsigned r = v.u + 0x7FFFu + ((v.u >> 16) & 1u);
  return (us)(r >> 16);
}
__device__ __forceinline__ float bf2f(us u){
  union { unsigned u; float f; } v; v.u = ((unsigned)u) << 16; return v.f;
}

// async global->LDS, 16B per lane; LDS dest = wave-uniform base + lane*16
__device__ __forceinline__ void gl_lds16(void* lds, const void* g){
  __builtin_amdgcn_global_load_lds(
      (const __attribute__((address_space(1))) unsigned int*)g,
      (__attribute__((address_space(3))) unsigned int*)lds, 16, 0, 0);
}

// ---------------------------------------------------------------------------
// k_pre: fused preprocessing, block-range dispatch.
#define G_RC 6
#define G_CW 1088
#define G_CAST 2496
#define G_HCAT 1872
#define G_PRE (G_RC + G_CW + G_CAST + G_HCAT)

__global__ __launch_bounds__(256) void k_pre(
    const float* __restrict__ W_ih, const float* __restrict__ W_z,
    const float* __restrict__ W_h, const float* __restrict__ answer_W,
    const float* __restrict__ zz_W, const float* __restrict__ W_hh,
    const float* __restrict__ p1_W, const float* __restrict__ p2_W,
    const float* __restrict__ emb, const int* __restrict__ q_next,
    const float* __restrict__ qmn, const float* __restrict__ q_m,
    float* __restrict__ rtab, us* __restrict__ wts,
    us* __restrict__ p1bf, us* __restrict__ p2bf,
    us* __restrict__ qbf, us* __restrict__ Abf)
{
  const int blk = blockIdx.x, tid = threadIdx.x;
  if (blk < G_RC){
    int which = blk >> 1, j = blk & 1, h = tid;
    if (h >= CC) return;
    const float* W; int stride;
    if (which==0){ W=W_ih; stride=379; } else if (which==1){ W=W_z; stride=502; } else { W=W_h; stride=502; }
    const float* a = answer_W + j*EMBD;
    const float* w = W + (size_t)h*stride + CC;
    float acc = 0.f;
    #pragma unroll 8
    for (int i=0;i<EMBD;i++) acc += w[i]*a[i];
    rtab[(which*2+j)*128 + h] = acc;
    return;
  }
  if (blk < G_RC + G_CW){
    int i = (blk - G_RC)*256 + tid;
    if (i < 7*16384){
      int w = i >> 14, idx = i & 16383, n = idx >> 7, k = idx & 127;
      float v = 0.f;
      if (n < CC && k < CC){
        if      (w==0) v = zz_W[n*CC + k];
        else if (w==1) v = W_ih[n*379 + k];
        else if (w==2) v = W_z [n*502 + k];
        else if (w==3) v = W_h [n*502 + k];
        else if (w==4) v = W_hh[n*CC + k];
        else if (w==5) v = W_z [n*502 + 379 + k];
        else           v = W_h [n*502 + 379 + k];
      }
      wts[i] = f2bf(v);
      return;
    }
    int j = i - 7*16384;
    if (j < 256*512){
      int n = j >> 9, k = j & 511;
      float v;
      if      (k < 379) v = p1_W[n*502 + k + 123];   // emb|qmn block (orig cols 123..501)
      else if (k < 384) v = 0.f;
      else if (k < 507) v = p1_W[n*502 + (k - 384)]; // out2 block (orig cols 0..122)
      else              v = 0.f;
      p1bf[j] = f2bf(v);
      return;
    }
    j -= 256*512;
    if (j < 128*256){
      int n = j >> 8, k = j & 255;
      p2bf[j] = f2bf(n < CC ? p2_W[n*256 + k] : 0.f);
    }
    return;
  }
  if (blk < G_RC + G_CW + G_CAST){
    const size_t total = (size_t)NRB*128;
    for (size_t i = (size_t)(blk - G_RC - G_CW)*256 + tid; i < total; i += (size_t)G_CAST*256){
      int col = (int)(i & 127); size_t rp = i >> 7;
      int t = (int)(rp >> 10), b = (int)(rp & 1023);
      float v = (col < CC) ? q_m[((size_t)b*TT + t)*CC + col] : 0.f;
      qbf[i] = f2bf(v);
    }
    return;
  }
  // hcat region: chunks of 8 cols, cols [0,384)
  {
    const size_t nchunk = (size_t)NRB*48;
    for (size_t c = (size_t)(blk - G_RC - G_CW - G_CAST)*256 + tid; c < nchunk; c += (size_t)G_HCAT*256){
      size_t row = c / 48;
      int c0 = (int)(c - row*48) * 8;
      short8 o;
      if (c0 < 256){
        int qn = q_next[row];
        float4 v0 = *(const float4*)(emb + (size_t)qn*EMBD + c0);
        float4 v1 = *(const float4*)(emb + (size_t)qn*EMBD + c0 + 4);
        o[0]=f2bf(v0.x); o[1]=f2bf(v0.y); o[2]=f2bf(v0.z); o[3]=f2bf(v0.w);
        o[4]=f2bf(v1.x); o[5]=f2bf(v1.y); o[6]=f2bf(v1.z); o[7]=f2bf(v1.w);
      } else {
        int j0 = c0 - 256;
        #pragma unroll
        for (int jj=0;jj<8;jj++){
          int j = j0 + jj;
          o[jj] = (j < CC) ? f2bf(qmn[row*CC + j]) : (short)0;
        }
      }
      *(short8*)(Abf + row*512 + c0) = o;
    }
  }
}

// ---------------------------------------------------------------------------
// k_zz_elem: AB = qbf @ zzW^T + zz_b (MFMA); epilogue writes swizzled
//  x1a (A-frag order), pre2/cq (C-frag order), all bf16.
__global__ __launch_bounds__(256) void k_zz_elem(
    const us* __restrict__ X, const us* __restrict__ W,
    const float* __restrict__ zz_b,
    const float* __restrict__ q_m, const int* __restrict__ s_id,
    const int* __restrict__ e_id, const float* __restrict__ student_W,
    const float* __restrict__ k_diff_W, const float* __restrict__ e_disc_W,
    const float* __restrict__ d_t_p, const float* __restrict__ d_e_p,
    us* __restrict__ x1a, us* __restrict__ pre2, us* __restrict__ cqb)
{
  __shared__ __align__(16) us Asl[16][64][8];   // 16 KB
  const int tid = threadIdx.x, w = tid >> 6, l = tid & 63, q = l >> 4, r16 = l & 15;
  const int rTile = blockIdx.x*64;
  short8 bfr[2][4];
  #pragma unroll
  for (int nt=0;nt<2;nt++){
    int n = w*32 + nt*16 + r16;
    #pragma unroll
    for (int kt=0;kt<4;kt++)
      bfr[nt][kt] = *(const short8*)(W + (size_t)n*128 + kt*32 + q*8);
  }
  #pragma unroll
  for (int i=0;i<4;i++){
    int seg = i*4 + w;
    gl_lds16(&Asl[seg][l][0], X + (size_t)(rTile+l)*128 + seg*8);
  }
  floatx4 acc[4][2];
  #pragma unroll
  for (int mt=0;mt<4;mt++){
    #pragma unroll
    for (int nt=0;nt<2;nt++){ acc[mt][nt][0]=0.f; acc[mt][nt][1]=0.f; acc[mt][nt][2]=0.f; acc[mt][nt][3]=0.f; }
  }
  __syncthreads();
  #pragma unroll
  for (int kt=0;kt<4;kt++){
    short8 af[4];
    #pragma unroll
    for (int mt=0;mt<4;mt++) af[mt] = *(const short8*)&Asl[kt*4+q][mt*16+r16][0];
    #pragma unroll
    for (int mt=0;mt<4;mt++){
      #pragma unroll
      for (int nt=0;nt<2;nt++)
        acc[mt][nt] = __builtin_amdgcn_mfma_f32_16x16x32_bf16(af[mt], bfr[nt][kt], acc[mt][nt], 0,0,0);
    }
  }
  const float dt = d_t_p[0], de = d_e_p[0];
  float zzb[2]; int colv[2];
  #pragma unroll
  for (int nt=0;nt<2;nt++){
    int col = w*32 + nt*16 + r16; colv[nt] = col;
    zzb[nt] = (col < CC) ? zz_b[col] : 0.f;
  }
  const int t = rTile >> 10;           // rows of this block share t (1024 % 64 == 0)
  #pragma unroll
  for (int mt=0;mt<4;mt++){
    #pragma unroll
    for (int i=0;i<4;i++){
      int row = rTile + mt*16 + q*4 + i;
      int b = row & 1023;
      int g = b*TT + t;
      int btile = b >> 4, r = b & 15;
      int sid = s_id[b];
      int e   = e_id[g];
      float ed = fsig(e_disc_W[e]) * de;
      size_t base = ((size_t)t*64 + btile)*2048;
      #pragma unroll
      for (int nt=0;nt<2;nt++){
        int col = colv[nt];
        float x1v = 0.f, p2v = 0.f, cqv = 0.f;
        if (col < CC){
          float ab = acc[mt][nt][i] + zzb[nt];
          float sp = fsig(student_W[(size_t)sid*CC + col]);
          float kd = fsig(k_diff_W[(size_t)e*CC + col]);
          float qv = q_m[(size_t)g*CC + col];
          x1v = ab*sp;
          p2v = ed*(dt*sp - kd)*qv;
          cqv = ed*(1.f - dt)*qv;
        }
        x1a[base + (size_t)(((col>>5)*64 + ((col>>3)&3)*16 + r)*8) + (col&7)] = f2bf(x1v);
        size_t off = base + (size_t)(((col>>5)*64 + ((r>>2))*16 + (col&15))*8) + ((col>>4)&1)*4 + (r&3);
        pre2[off] = f2bf(p2v);
        cqb[off]  = f2bf(cqv);
      }
    }
  }
}

// ---------------------------------------------------------------------------
// k_mid: fused rnn1 + (Zx,Hx) + rnn2, ONE barrier per step, register inputs.
// 512 threads = 8 waves x 16 cols each; 64 blocks x 16 batch rows.
__global__ __launch_bounds__(512,1) void k_mid(
    const us* __restrict__ x1a, const us* __restrict__ pre2, const us* __restrict__ cqb,
    const us* __restrict__ Wih, const us* __restrict__ Whh,
    const us* __restrict__ Wzx, const us* __restrict__ Whx,
    const us* __restrict__ Wzh, const us* __restrict__ Whh2,
    const float* __restrict__ b_ih, const float* __restrict__ b_z, const float* __restrict__ b_h,
    const float* __restrict__ W_tg, const float* __restrict__ b_tg,
    const float* __restrict__ rtab, const int* __restrict__ r_idx,
    us* __restrict__ Abf)
{
  __shared__ __align__(16) us h1s[2][16*PCH];
  __shared__ __align__(16) us x2s[2][16*PCH];
  __shared__ __align__(16) us h2s[2][16*PCH];
  __shared__ int rint[TT*16];
  const int tid = threadIdx.x, w = tid >> 6, l = tid & 63, q = l >> 4, r16 = l & 15;
  const int bbase = blockIdx.x*16;
  const int n = w*16 + r16;                 // output column 0..127

  short8 fih[4], fhh[4], fzx[4], fhx[4], fzh[4], fh2w[4];
  #pragma unroll
  for (int kt=0;kt<4;kt++){
    size_t wofs = (size_t)n*128 + kt*32 + q*8;
    fih[kt]  = *(const short8*)(Wih  + wofs);
    fhh[kt]  = *(const short8*)(Whh  + wofs);
    fzx[kt]  = *(const short8*)(Wzx  + wofs);
    fhx[kt]  = *(const short8*)(Whx  + wofs);
    fzh[kt]  = *(const short8*)(Wzh  + wofs);
    fh2w[kt] = *(const short8*)(Whh2 + wofs);
  }
  const bool vc = n < CC;
  const float bih = vc? b_ih[n]:0.f, bzv = vc? b_z[n]:0.f, bhv = vc? b_h[n]:0.f;
  const float wg = vc? W_tg[n]:0.f, bg = vc? b_tg[n]:0.f;
  const float r10 = vc? rtab[n]:0.f,     r11 = vc? rtab[128+n]:0.f;
  const float r20 = vc? rtab[256+n]:0.f, r21 = vc? rtab[384+n]:0.f;
  const float r30 = vc? rtab[512+n]:0.f, r31 = vc? rtab[640+n]:0.f;

  for (int i = tid; i < TT*16; i += 512)
    rint[i] = r_idx[(size_t)(bbase + (i & 15))*TT + (i >> 4)];
  for (int i = tid; i < 16*PCH; i += 512){ h1s[1][i] = 0; h2s[1][i] = 0; }

  short8 x1c[4];
  shortv4 pc4, cc4;
  {
    size_t base = (size_t)blockIdx.x*2048;   // t=0 tile
    #pragma unroll
    for (int kt=0;kt<4;kt++)
      x1c[kt] = *(const short8*)(x1a + base + (size_t)(kt*64 + q*16 + r16)*8);
    size_t cofs = base + (size_t)((w>>1)*64 + q*16 + r16)*8 + (size_t)(w&1)*4;
    pc4 = *(const shortv4*)(pre2 + cofs);
    cc4 = *(const shortv4*)(cqb + cofs);
  }
  __syncthreads();

  floatx4 accx;
  #pragma unroll
  for (int i=0;i<4;i++){ int rs = rint[q*4 + i]; accx[i] = bih + (rs ? r11 : r10); }
  #pragma unroll
  for (int kt=0;kt<4;kt++)
    accx = __builtin_amdgcn_mfma_f32_16x16x32_bf16(x1c[kt], fih[kt], accx, 0,0,0);

  floatx4 hold; hold[0]=0.f; hold[1]=0.f; hold[2]=0.f; hold[3]=0.f;

  for (int t=0; t<TT; t++){
    const int pA = t & 1, pO = pA ^ 1;
    short8 x1n[4]; shortv4 pcn, ccn;
    if (t < TT-1){
      size_t base = ((size_t)(t+1)*64 + blockIdx.x)*2048;
      #pragma unroll
      for (int kt=0;kt<4;kt++)
        x1n[kt] = *(const short8*)(x1a + base + (size_t)(kt*64 + q*16 + r16)*8);
      size_t cofs = base + (size_t)((w>>1)*64 + q*16 + r16)*8 + (size_t)(w&1)*4;
      pcn = *(const shortv4*)(pre2 + cofs);
      ccn = *(const shortv4*)(cqb + cofs);
    }
    // ---- stage A: h1 recurrence + x2a production (pre-barrier)
    short8 fr1[4];
    #pragma unroll
    for (int kt=0;kt<4;kt++)
      fr1[kt] = *(const short8*)&h1s[pO][r16*PCH + kt*32 + q*8];
    floatx4 acc1 = accx;
    #pragma unroll
    for (int kt=0;kt<4;kt++)
      acc1 = __builtin_amdgcn_mfma_f32_16x16x32_bf16(fr1[kt], fhh[kt], acc1, 0,0,0);
    float g = fsig((float)t*wg + bg);
    #pragma unroll
    for (int i=0;i<4;i++){
      float h1v = ftanh(acc1[i]) * g;
      h1s[pA][(q*4+i)*PCH + n] = f2bf(h1v);
      float xv = bf2f((us)pc4[i]) + bf2f((us)cc4[i])*h1v;
      x2s[pA][(q*4+i)*PCH + n] = f2bf(xv);
    }
    __syncthreads();
    // ---- stage B: h2 recurrence + next-step Xp precompute (post-barrier)
    if (t >= 1 && tid < 256){
      int row = tid >> 4, cs = tid & 15;
      short8 hv8 = *(const short8*)&h2s[pO][row*PCH + cs*8];
      *(short8*)(Abf + ((size_t)(bbase + row)*TT + (t-1))*512 + 384 + cs*8) = hv8;
    }
    short8 fx[4], fh[4];
    #pragma unroll
    for (int kt=0;kt<4;kt++){
      fx[kt] = *(const short8*)&x2s[pA][r16*PCH + kt*32 + q*8];
      fh[kt] = *(const short8*)&h2s[pO][r16*PCH + kt*32 + q*8];
    }
    floatx4 az, ahh;
    #pragma unroll
    for (int i=0;i<4;i++){
      int rs = rint[t*16 + q*4 + i];
      az[i]  = bzv + (rs ? r21 : r20);
      ahh[i] = bhv + (rs ? r31 : r30);
    }
    #pragma unroll
    for (int kt=0;kt<4;kt++){
      az  = __builtin_amdgcn_mfma_f32_16x16x32_bf16(fx[kt], fzx[kt], az, 0,0,0);
      az  = __builtin_amdgcn_mfma_f32_16x16x32_bf16(fh[kt], fzh[kt], az, 0,0,0);
      ahh = __builtin_amdgcn_mfma_f32_16x16x32_bf16(fx[kt], fhx[kt], ahh, 0,0,0);
      ahh = __builtin_amdgcn_mfma_f32_16x16x32_bf16(fh[kt], fh2w[kt], ahh, 0,0,0);
    }
    #pragma unroll
    for (int i=0;i<4;i++){
      float z  = fsig(az[i]);
      float th = ftanh(ahh[i]);
      hold[i] += z*(th - hold[i]);
      h2s[pA][(q*4+i)*PCH + n] = f2bf(hold[i]);
    }
    if (t < TT-1){
      #pragma unroll
      for (int i=0;i<4;i++){ int rs = rint[(t+1)*16 + q*4 + i]; accx[i] = bih + (rs ? r11 : r10); }
      #pragma unroll
      for (int kt=0;kt<4;kt++)
        accx = __builtin_amdgcn_mfma_f32_16x16x32_bf16(x1n[kt], fih[kt], accx, 0,0,0);
      pc4 = pcn; cc4 = ccn;
    }
  }
  __syncthreads();
  if (tid < 256){
    int row = tid >> 4, cs = tid & 15;
    short8 hv8 = *(const short8*)&h2s[(TT-1)&1][row*PCH + cs*8];
    *(short8*)(Abf + ((size_t)(bbase + row)*TT + (TT-1))*512 + 384 + cs*8) = hv8;
  }
}

// ---------------------------------------------------------------------------
// k_out: o1 = sigmoid(Abf @ p1bf^T + p1_b) kept in LDS (bf16),
//        o2 = sigmoid(o1 @ p2bf^T + p2_b), out = sigmoid(o2 @ p3 + p3_b).
__global__ __launch_bounds__(256) void k_out(
    const us* __restrict__ Abf, const us* __restrict__ p1bf,
    const float* __restrict__ p1_b, const us* __restrict__ p2bf,
    const float* __restrict__ p2_b, const float* __restrict__ p3_W,
    const float* __restrict__ p3_b, float* __restrict__ out)
{
  __shared__ __align__(16) us smem[20480];   // 40 KB: Asl(4096) + Bsl(16384); o1s aliases (16896)
  __shared__ float red[64][4];
  us* Asl = smem;            // [seg<8][m<64][8]
  us* Bsl = smem + 4096;     // [seg<8][n<256][8]
  us* o1s = smem;            // [row<64][264] (aliased after phase 1)
  const int tid = threadIdx.x;
  const int w = tid >> 6, l = tid & 63;
  const int q = l >> 4, r16 = l & 15;
  const int rTile = blockIdx.x * 64;
  floatx4 acc[4][4];
  #pragma unroll
  for (int a=0;a<4;a++){
    #pragma unroll
    for (int b=0;b<4;b++){ acc[a][b][0]=0.f; acc[a][b][1]=0.f; acc[a][b][2]=0.f; acc[a][b][3]=0.f; }
  }
  for (int c = 0; c < 8; c++){
    const int k0 = c*64;
    #pragma unroll
    for (int i=0;i<2;i++){
      int u = i*256 + tid; int seg = u>>6, m = u&63;
      gl_lds16(&Asl[(seg*64 + m)*8], Abf + (size_t)(rTile+m)*512 + k0 + seg*8);
    }
    #pragma unroll
    for (int i=0;i<8;i++){
      int u = i*256 + tid; int seg = u>>8, nn = u&255;
      gl_lds16(&Bsl[(seg*256 + nn)*8], p1bf + (size_t)nn*512 + k0 + seg*8);
    }
    __syncthreads();
    #pragma unroll
    for (int ks=0; ks<2; ks++){
      int seg = ks*4 + q;
      short8 af[4], bfr[4];
      #pragma unroll
      for (int mt=0;mt<4;mt++) af[mt] = *(const short8*)&Asl[(seg*64 + mt*16 + r16)*8];
      #pragma unroll
      for (int nt=0;nt<4;nt++) bfr[nt] = *(const short8*)&Bsl[(seg*256 + w*64 + nt*16 + r16)*8];
      #pragma unroll
      for (int mt=0;mt<4;mt++){
        #pragma unroll
        for (int nt=0;nt<4;nt++)
          acc[mt][nt] = __builtin_amdgcn_mfma_f32_16x16x32_bf16(af[mt], bfr[nt], acc[mt][nt], 0,0,0);
      }
    }
    __syncthreads();
  }
  // ---- write o1 (sigmoid) into LDS, row-major pitch 264
  #pragma unroll
  for (int nt=0;nt<4;nt++){
    int col = w*64 + nt*16 + r16;
    float bb = p1_b[col];
    #pragma unroll
    for (int mt=0;mt<4;mt++){
      #pragma unroll
      for (int i=0;i<4;i++)
        o1s[(mt*16 + q*4 + i)*264 + col] = f2bf(fsig(acc[mt][nt][i] + bb));
    }
  }
  __syncthreads();
  // ---- phase 2: o2 GEMM (M=64, N=128, K=256) + p3 reduction
  short8 bf2[2][8];
  #pragma unroll
  for (int nt=0;nt<2;nt++){
    int n2 = w*32 + nt*16 + r16;
    #pragma unroll
    for (int kt=0;kt<8;kt++)
      bf2[nt][kt] = *(const short8*)(p2bf + (size_t)n2*256 + kt*32 + q*8);
  }
  floatx4 ac2[4][2];
  #pragma unroll
  for (int mt=0;mt<4;mt++){
    #pragma unroll
    for (int nt=0;nt<2;nt++){ ac2[mt][nt][0]=0.f; ac2[mt][nt][1]=0.f; ac2[mt][nt][2]=0.f; ac2[mt][nt][3]=0.f; }
  }
  #pragma unroll
  for (int kt=0;kt<8;kt++){
    short8 af[4];
    #pragma unroll
    for (int mt=0;mt<4;mt++) af[mt] = *(const short8*)&o1s[(mt*16 + r16)*264 + kt*32 + q*8];
    #pragma unroll
    for (int mt=0;mt<4;mt++){
      #pragma unroll
      for (int nt=0;nt<2;nt++)
        ac2[mt][nt] = __builtin_amdgcn_mfma_f32_16x16x32_bf16(af[mt], bf2[nt][kt], ac2[mt][nt], 0,0,0);
    }
  }
  const int n0 = w*32 + r16, n1 = n0 + 16;
  const float pb0 = (n0<CC)? p2_b[n0]:0.f, pb1 = (n1<CC)? p2_b[n1]:0.f;
  const float p30 = (n0<CC)? p3_W[n0]:0.f, p31 = (n1<CC)? p3_W[n1]:0.f;
  #pragma unroll
  for (int mt=0;mt<4;mt++){
    #pragma unroll
    for (int i=0;i<4;i++){
      float s = fsig(ac2[mt][0][i]+pb0)*p30 + fsig(ac2[mt][1][i]+pb1)*p31;
      s += __shfl_xor(s,1,16); s += __shfl_xor(s,2,16);
      s += __shfl_xor(s,4,16); s += __shfl_xor(s,8,16);
      if (r16==0) red[mt*16 + q*4 + i][w] = s;
    }
  }
  __syncthreads();
  if (tid < 64){
    float o = red[tid][0]+red[tid][1]+red[tid][2]+red[tid][3] + p3_b[0];
    out[rTile + tid] = fsig(o);
  }
}

// ---------------------------------------------------------------------------
extern "C" void kernel_launch(void* const* d_in, const int* in_sizes, int n_in,
                              void* d_out, int out_size, void* d_ws, size_t ws_size,
                              hipStream_t stream) {
  const float* q_m       = (const float*)d_in[0];
  const float* q_m_next  = (const float*)d_in[1];
  const int*   s_id      = (const int*)d_in[3];
  const int*   e_id      = (const int*)d_in[4];
  const int*   r_idx     = (const int*)d_in[5];
  const int*   q_next    = (const int*)d_in[6];
  const float* emb_problem = (const float*)d_in[8];
  const float* student_W = (const float*)d_in[9];
  const float* k_diff_W  = (const float*)d_in[10];
  const float* e_disc_W  = (const float*)d_in[11];
  const float* answer_W  = (const float*)d_in[12];
  const float* zz_W      = (const float*)d_in[13];
  const float* zz_b      = (const float*)d_in[14];
  const float* d_t       = (const float*)d_in[15];
  const float* d_e       = (const float*)d_in[16];
  const float* W_ih      = (const float*)d_in[17];
  const float* b_ih      = (const float*)d_in[18];
  const float* W_hh      = (const float*)d_in[19];
  const float* W_tg      = (const float*)d_in[21];
  const float* b_tg      = (const float*)d_in[22];
  const float* W_z       = (const float*)d_in[23];
  const float* b_z       = (const float*)d_in[24];
  const float* W_h       = (const float*)d_in[25];
  const float* b_h       = (const float*)d_in[26];
  const float* p1_W      = (const float*)d_in[27];
  const float* p1_b      = (const float*)d_in[28];
  const float* p2_W      = (const float*)d_in[29];
  const float* p2_b      = (const float*)d_in[30];
  const float* p3_W      = (const float*)d_in[31];
  const float* p3_b      = (const float*)d_in[32];

  float* ws   = (float*)d_ws;
  float* rtab = ws;                                   // 1024 f32
  us* qbf  = (us*)(ws + 1024);                        // [NRB][128]
  us* x1a  = qbf  + (size_t)NRB*128;                  // swizzled [t][btile][2048]
  us* pre2 = x1a  + (size_t)NRB*128;
  us* cqb  = pre2 + (size_t)NRB*128;
  us* Abf  = cqb  + (size_t)NRB*128;                  // [NRB][512]
  us* wts  = Abf  + (size_t)NRB*512;                  // 7*[128][128]
  us* p1bf = wts  + 7*16384;                          // [256][512]
  us* p2bf = p1bf + 256*512;                          // [128][256]

  const us* zzWbf  = wts + 0*16384;
  const us* Wih123 = wts + 1*16384;
  const us* Wz123  = wts + 2*16384;
  const us* Wh123  = wts + 3*16384;
  const us* Whhbf  = wts + 4*16384;
  const us* Wzhbf  = wts + 5*16384;
  const us* Whh2bf = wts + 6*16384;

  hipLaunchKernelGGL(k_pre, dim3(G_PRE), dim3(256), 0, stream,
                     W_ih, W_z, W_h, answer_W, zz_W, W_hh, p1_W, p2_W,
                     emb_problem, q_next, q_m_next, q_m,
                     rtab, wts, p1bf, p2bf, qbf, Abf);
  hipLaunchKernelGGL(k_zz_elem, dim3(NRB/64), dim3(256), 0, stream,
                     qbf, zzWbf, zz_b, q_m, s_id, e_id, student_W, k_diff_W,
                     e_disc_W, d_t, d_e, x1a, pre2, cqb);
  hipLaunchKernelGGL(k_mid, dim3(BB/16), dim3(512), 0, stream,
                     x1a, pre2, cqb, Wih123, Whhbf, Wz123, Wh123, Wzhbf, Whh2bf,
                     b_ih, b_z, b_h, W_tg, b_tg, rtab, r_idx, Abf);
  hipLaunchKernelGGL(k_out, dim3(NRB/64), dim3(256), 0, stream,
                     Abf, p1bf, p1_b, p2bf, p2_b, p3_W, p3_b, (float*)d_out);
}